// Round 1
// baseline (707.967 us; speedup 1.0000x reference)
//
#include <hip/hip_runtime.h>
#include <hip/hip_bf16.h>

#define NH 12
#define SEQ 4096
#define E 768
#define DK 64

typedef float f32x4 __attribute__((ext_vector_type(4)));
typedef __bf16 bf16x8 __attribute__((ext_vector_type(8)));

#define MFMA16(a, b, c) __builtin_amdgcn_mfma_f32_16x16x32_bf16((a), (b), (c), 0, 0, 0)

// log2(e) / sqrt(dk) = 1.4426950408889634 / 8
#define SCL 0.18033688011112042f

// ---------------------------------------------------------------------------
// Kernel 1: split projection weights into bf16 hi/lo and transpose to [h][n][k]
// so MFMA B-fragments (B[k][n], lane holds 8 contiguous k at row n=lane&15)
// are single 16B loads.
// ---------------------------------------------------------------------------
__global__ void wsplit_kernel(const float* __restrict__ qp,
                              const float* __restrict__ kp,
                              const float* __restrict__ vp,
                              __bf16* __restrict__ wtq_h, __bf16* __restrict__ wtq_l,
                              __bf16* __restrict__ wtk_h, __bf16* __restrict__ wtk_l,
                              __bf16* __restrict__ wtv_h) {
    int idx = blockIdx.x * blockDim.x + threadIdx.x;
    if (idx >= NH * E * DK) return;
    int h = idx / (E * DK);
    int rem = idx - h * E * DK;
    int k = rem / DK;
    int n = rem - k * DK;
    int o = h * DK * E + n * E + k;   // [h][n][k]
    float q = qp[idx];
    __bf16 qh = (__bf16)q;
    wtq_h[o] = qh;
    wtq_l[o] = (__bf16)(q - (float)qh);
    float kk = kp[idx];
    __bf16 kh = (__bf16)kk;
    wtk_h[o] = kh;
    wtk_l[o] = (__bf16)(kk - (float)kh);
    wtv_h[o] = (__bf16)vp[idx];
}

// ---------------------------------------------------------------------------
// Kernel 2: fused QKV projection. One block = 1 head x 64 rows, 4 waves,
// each wave computes 16 rows x 64 cols for Q, K, V.
// Q,K in split precision (3 MFMA terms); V plain bf16 (1 term).
// Q,K stored [h][s][d] as hi/lo; V stored transposed [h][d][s].
// ---------------------------------------------------------------------------
__global__ __launch_bounds__(256) void qkv_proj_kernel(
    const float* __restrict__ x,
    const __bf16* __restrict__ wtq_h, const __bf16* __restrict__ wtq_l,
    const __bf16* __restrict__ wtk_h, const __bf16* __restrict__ wtk_l,
    const __bf16* __restrict__ wtv_h,
    __bf16* __restrict__ qh_o, __bf16* __restrict__ ql_o,
    __bf16* __restrict__ kh_o, __bf16* __restrict__ kl_o,
    __bf16* __restrict__ vt_o) {
    const int head = blockIdx.x / 64;
    const int rb = blockIdx.x % 64;
    const int wave = threadIdx.x >> 6;
    const int lane = threadIdx.x & 63;
    const int row0 = rb * 64 + wave * 16;
    const int lrow = lane & 15;
    const int lk8 = (lane >> 4) * 8;

    f32x4 accq[4], acck[4], accv[4];
#pragma unroll
    for (int f = 0; f < 4; ++f) {
        accq[f] = (f32x4){0.f, 0.f, 0.f, 0.f};
        acck[f] = (f32x4){0.f, 0.f, 0.f, 0.f};
        accv[f] = (f32x4){0.f, 0.f, 0.f, 0.f};
    }

    const float* xrow = x + (size_t)(row0 + lrow) * E + lk8;
    const __bf16* wq_h = wtq_h + head * DK * E;
    const __bf16* wq_l = wtq_l + head * DK * E;
    const __bf16* wk_h = wtk_h + head * DK * E;
    const __bf16* wk_l = wtk_l + head * DK * E;
    const __bf16* wv_h = wtv_h + head * DK * E;

    for (int ks = 0; ks < E / 32; ++ks) {
        float xv[8];
        *(float4*)&xv[0] = *(const float4*)(xrow + ks * 32);
        *(float4*)&xv[4] = *(const float4*)(xrow + ks * 32 + 4);
        bf16x8 a_h, a_l;
#pragma unroll
        for (int i = 0; i < 8; ++i) {
            __bf16 hh = (__bf16)xv[i];
            a_h[i] = hh;
            a_l[i] = (__bf16)(xv[i] - (float)hh);
        }
#pragma unroll
        for (int f = 0; f < 4; ++f) {
            int wo = (f * 16 + lrow) * E + ks * 32 + lk8;
            bf16x8 bqh = *(const bf16x8*)(wq_h + wo);
            bf16x8 bql = *(const bf16x8*)(wq_l + wo);
            bf16x8 bkh = *(const bf16x8*)(wk_h + wo);
            bf16x8 bkl = *(const bf16x8*)(wk_l + wo);
            bf16x8 bvh = *(const bf16x8*)(wv_h + wo);
            accq[f] = MFMA16(a_h, bqh, accq[f]);
            accq[f] = MFMA16(a_h, bql, accq[f]);
            accq[f] = MFMA16(a_l, bqh, accq[f]);
            acck[f] = MFMA16(a_h, bkh, acck[f]);
            acck[f] = MFMA16(a_h, bkl, acck[f]);
            acck[f] = MFMA16(a_l, bkh, acck[f]);
            accv[f] = MFMA16(a_h, bvh, accv[f]);
        }
    }

    // D layout: row = (lane>>4)*4 + r, col = f*16 + (lane&15)
#pragma unroll
    for (int f = 0; f < 4; ++f) {
#pragma unroll
        for (int r = 0; r < 4; ++r) {
            int srow = row0 + (lane >> 4) * 4 + r;
            int d = f * 16 + lrow;
            size_t qko = (size_t)head * SEQ * DK + (size_t)srow * DK + d;
            float qv = accq[f][r];
            __bf16 qhh = (__bf16)qv;
            qh_o[qko] = qhh;
            ql_o[qko] = (__bf16)(qv - (float)qhh);
            float kv = acck[f][r];
            __bf16 khh = (__bf16)kv;
            kh_o[qko] = khh;
            kl_o[qko] = (__bf16)(kv - (float)khh);
            vt_o[(size_t)head * DK * SEQ + (size_t)d * SEQ + srow] = (__bf16)accv[f][r];
        }
    }
}

// ---------------------------------------------------------------------------
// Kernel 3: causal flash attention. One block = 1 wave = 16 q-rows of one head.
// K tiles of 64 cols; QK^T in split bf16 (3 terms); online softmax in fp32;
// P -> LDS (bf16, XOR-swizzled) -> A-fragment; PV in plain bf16.
// ---------------------------------------------------------------------------
__global__ __launch_bounds__(64) void attn_kernel(
    const __bf16* __restrict__ qh, const __bf16* __restrict__ ql,
    const __bf16* __restrict__ kh, const __bf16* __restrict__ kl,
    const __bf16* __restrict__ vt,
    float* __restrict__ out) {
    __shared__ __bf16 plds[16 * 64];  // 2 KB

    const int head = blockIdx.x >> 8;
    const int rb = blockIdx.x & 255;
    const int q0 = rb * 16;
    const int lane = threadIdx.x;
    const int lrow = lane & 15;
    const int lk8 = (lane >> 4) * 8;
    const int g4 = (lane >> 4) * 4;

    // Q fragments (hoisted): ks = 0,1 over d
    const __bf16* qh_p = qh + (size_t)head * SEQ * DK + (size_t)(q0 + lrow) * DK + lk8;
    const __bf16* ql_p = ql + (size_t)head * SEQ * DK + (size_t)(q0 + lrow) * DK + lk8;
    bf16x8 qhf[2], qlf[2];
    qhf[0] = *(const bf16x8*)(qh_p);
    qhf[1] = *(const bf16x8*)(qh_p + 32);
    qlf[0] = *(const bf16x8*)(ql_p);
    qlf[1] = *(const bf16x8*)(ql_p + 32);

    const __bf16* kh_b = kh + (size_t)head * SEQ * DK;
    const __bf16* kl_b = kl + (size_t)head * SEQ * DK;
    const __bf16* vt_b = vt + (size_t)head * DK * SEQ;

    f32x4 O[4];
    float m[4], l[4];
#pragma unroll
    for (int i = 0; i < 4; ++i) {
        O[i] = (f32x4){0.f, 0.f, 0.f, 0.f};
        m[i] = -3.0e38f;
        l[i] = 0.f;
    }

    const int kb0 = q0 & ~63;
    for (int kb = 0; kb <= kb0; kb += 64) {
        // ---- S = Q K^T (raw, unscaled) ----
        f32x4 sf[4];
#pragma unroll
        for (int f = 0; f < 4; ++f) {
            f32x4 acc = (f32x4){0.f, 0.f, 0.f, 0.f};
#pragma unroll
            for (int ks = 0; ks < 2; ++ks) {
                size_t ko = (size_t)(kb + f * 16 + lrow) * DK + ks * 32 + lk8;
                bf16x8 bh = *(const bf16x8*)(kh_b + ko);
                bf16x8 bl = *(const bf16x8*)(kl_b + ko);
                acc = MFMA16(qhf[ks], bh, acc);
                acc = MFMA16(qhf[ks], bl, acc);
                acc = MFMA16(qlf[ks], bh, acc);
            }
            sf[f] = acc;
        }
        // ---- causal mask (diagonal tile only) ----
        if (kb == kb0) {
#pragma unroll
            for (int f = 0; f < 4; ++f)
#pragma unroll
                for (int r = 0; r < 4; ++r) {
                    int col = kb + f * 16 + lrow;
                    int row = q0 + g4 + r;
                    if (col > row) sf[f][r] = -1.0e30f;
                }
        }
        // ---- online softmax (fp32, raw-score max, scale folded in exp2) ----
        float alpha[4];
#pragma unroll
        for (int r = 0; r < 4; ++r) {
            float mx = fmaxf(fmaxf(sf[0][r], sf[1][r]), fmaxf(sf[2][r], sf[3][r]));
#pragma unroll
            for (int off = 1; off < 16; off <<= 1)
                mx = fmaxf(mx, __shfl_xor(mx, off));
            float mnew = fmaxf(m[r], mx);
            alpha[r] = exp2f((m[r] - mnew) * SCL);
            m[r] = mnew;
        }
#pragma unroll
        for (int f = 0; f < 4; ++f)
#pragma unroll
            for (int r = 0; r < 4; ++r)
                sf[f][r] = exp2f((sf[f][r] - m[r]) * SCL);
#pragma unroll
        for (int r = 0; r < 4; ++r) {
            float s = (sf[0][r] + sf[1][r]) + (sf[2][r] + sf[3][r]);
#pragma unroll
            for (int off = 1; off < 16; off <<= 1)
                s += __shfl_xor(s, off);
            l[r] = l[r] * alpha[r] + s;
        }
#pragma unroll
        for (int df = 0; df < 4; ++df)
#pragma unroll
            for (int r = 0; r < 4; ++r)
                O[df][r] *= alpha[r];

        // ---- P -> LDS (bf16, XOR swizzle to kill 128B-stride bank conflicts) ----
        __syncthreads();  // previous iteration's P reads complete
#pragma unroll
        for (int f = 0; f < 4; ++f)
#pragma unroll
            for (int r = 0; r < 4; ++r) {
                int rl = g4 + r;
                int bo = rl * 128 + (f * 16 + lrow) * 2;
                bo ^= (rl & 7) << 4;
                *(__bf16*)((char*)plds + bo) = (__bf16)sf[f][r];
            }
        __syncthreads();  // writes visible before reads
        bf16x8 pf[2];
#pragma unroll
        for (int ks = 0; ks < 2; ++ks) {
            int bo = lrow * 128 + (ks * 32 + lk8) * 2;
            bo ^= (lrow & 7) << 4;
            pf[ks] = *(const bf16x8*)((const char*)plds + bo);
        }
        // ---- O += P V ----
#pragma unroll
        for (int df = 0; df < 4; ++df) {
#pragma unroll
            for (int ks = 0; ks < 2; ++ks) {
                bf16x8 vf = *(const bf16x8*)(vt_b + (size_t)(df * 16 + lrow) * SEQ + kb + ks * 32 + lk8);
                O[df] = MFMA16(pf[ks], vf, O[df]);
            }
        }
    }

    // ---- epilogue: out[h][s][d] = O / l ----
#pragma unroll
    for (int df = 0; df < 4; ++df)
#pragma unroll
        for (int r = 0; r < 4; ++r) {
            int srow = q0 + g4 + r;
            out[(size_t)head * SEQ * DK + (size_t)srow * DK + df * 16 + lrow] = O[df][r] / l[r];
        }
}

// ---------------------------------------------------------------------------
extern "C" void kernel_launch(void* const* d_in, const int* in_sizes, int n_in,
                              void* d_out, int out_size, void* d_ws, size_t ws_size,
                              hipStream_t stream) {
    const float* x = (const float*)d_in[0];
    const float* qp = (const float*)d_in[1];
    const float* kp = (const float*)d_in[2];
    const float* vp = (const float*)d_in[3];
    float* out = (float*)d_out;

    const size_t WT_SZ = (size_t)NH * DK * E * 2;    // 1,179,648 B
    const size_t QKV_SZ = (size_t)NH * SEQ * DK * 2; // 6,291,456 B
    char* ws = (char*)d_ws;
    __bf16* wtq_h = (__bf16*)(ws + 0 * WT_SZ);
    __bf16* wtq_l = (__bf16*)(ws + 1 * WT_SZ);
    __bf16* wtk_h = (__bf16*)(ws + 2 * WT_SZ);
    __bf16* wtk_l = (__bf16*)(ws + 3 * WT_SZ);
    __bf16* wtv_h = (__bf16*)(ws + 4 * WT_SZ);
    char* p2 = ws + 5 * WT_SZ;
    __bf16* qh = (__bf16*)(p2 + 0 * QKV_SZ);
    __bf16* ql = (__bf16*)(p2 + 1 * QKV_SZ);
    __bf16* kh = (__bf16*)(p2 + 2 * QKV_SZ);
    __bf16* kl = (__bf16*)(p2 + 3 * QKV_SZ);
    __bf16* vt = (__bf16*)(p2 + 4 * QKV_SZ);
    // total ws use: ~37.4 MB

    hipLaunchKernelGGL(wsplit_kernel, dim3((NH * E * DK + 255) / 256), dim3(256), 0, stream,
                       qp, kp, vp, wtq_h, wtq_l, wtk_h, wtk_l, wtv_h);
    hipLaunchKernelGGL(qkv_proj_kernel, dim3(NH * 64), dim3(256), 0, stream,
                       x, wtq_h, wtq_l, wtk_h, wtk_l, wtv_h, qh, ql, kh, kl, vt);
    hipLaunchKernelGGL(attn_kernel, dim3(NH * 256), dim3(64), 0, stream,
                       qh, ql, kh, kl, vt, out);
}

// Round 2
// 413.954 us; speedup vs baseline: 1.7103x; 1.7103x over previous
//
#include <hip/hip_runtime.h>
#include <hip/hip_bf16.h>

#define NH 12
#define SEQ 4096
#define E 768
#define DK 64

typedef float f32x4 __attribute__((ext_vector_type(4)));
typedef __bf16 bf16x8 __attribute__((ext_vector_type(8)));
typedef __bf16 bf16x4 __attribute__((ext_vector_type(4)));

#define MFMA16(a, b, c) __builtin_amdgcn_mfma_f32_16x16x32_bf16((a), (b), (c), 0, 0, 0)

// log2(e) / sqrt(dk) = 1.4426950408889634 / 8
#define SCL 0.18033688011112042f

// ---------------------------------------------------------------------------
// DPP rotate-reduce within 16-lane rows (no LDS traffic, unlike __shfl_xor)
// ---------------------------------------------------------------------------
template <int N>
__device__ __forceinline__ float ror16(float x) {
    return __int_as_float(__builtin_amdgcn_update_dpp(
        0, __float_as_int(x), 0x120 | N, 0xf, 0xf, false));
}
__device__ __forceinline__ float rmax16(float v) {
    v = fmaxf(v, ror16<1>(v));
    v = fmaxf(v, ror16<2>(v));
    v = fmaxf(v, ror16<4>(v));
    v = fmaxf(v, ror16<8>(v));
    return v;
}
__device__ __forceinline__ float rsum16(float v) {
    v += ror16<1>(v);
    v += ror16<2>(v);
    v += ror16<4>(v);
    v += ror16<8>(v);
    return v;
}

__device__ __forceinline__ void gload16(const void* g, void* l) {
    __builtin_amdgcn_global_load_lds(
        (const __attribute__((address_space(1))) void*)g,
        (__attribute__((address_space(3))) void*)l, 16, 0, 0);
}

// ---------------------------------------------------------------------------
// Kernel 0: split x into bf16 hi/lo (once, instead of per-head repack)
// ---------------------------------------------------------------------------
__global__ __launch_bounds__(256) void xsplit_kernel(const float* __restrict__ x,
                                                     __bf16* __restrict__ xh,
                                                     __bf16* __restrict__ xl) {
    int i = blockIdx.x * blockDim.x + threadIdx.x;  // one float4 per thread
    float4 v = ((const float4*)x)[i];
    bf16x4 h, l;
    float vv[4] = {v.x, v.y, v.z, v.w};
#pragma unroll
    for (int j = 0; j < 4; ++j) {
        __bf16 hh = (__bf16)vv[j];
        h[j] = hh;
        l[j] = (__bf16)(vv[j] - (float)hh);
    }
    ((bf16x4*)xh)[i] = h;
    ((bf16x4*)xl)[i] = l;
}

// ---------------------------------------------------------------------------
// Kernel 1: split projection weights into bf16 hi/lo, transpose to [h][n][k]
// ---------------------------------------------------------------------------
__global__ void wsplit_kernel(const float* __restrict__ qp,
                              const float* __restrict__ kp,
                              const float* __restrict__ vp,
                              __bf16* __restrict__ wtq_h, __bf16* __restrict__ wtq_l,
                              __bf16* __restrict__ wtk_h, __bf16* __restrict__ wtk_l,
                              __bf16* __restrict__ wtv_h) {
    int idx = blockIdx.x * blockDim.x + threadIdx.x;
    if (idx >= NH * E * DK) return;
    int h = idx / (E * DK);
    int rem = idx - h * E * DK;
    int k = rem / DK;
    int n = rem - k * DK;
    int o = h * DK * E + n * E + k;  // [h][n][k]
    float q = qp[idx];
    __bf16 qh = (__bf16)q;
    wtq_h[o] = qh;
    wtq_l[o] = (__bf16)(q - (float)qh);
    float kk = kp[idx];
    __bf16 kh = (__bf16)kk;
    wtk_h[o] = kh;
    wtk_l[o] = (__bf16)(kk - (float)kh);
    wtv_h[o] = (__bf16)vp[idx];
}

// ---------------------------------------------------------------------------
// Kernel 2: fused QKV projection (xh/xl precomputed). Block = 1 head x 64 rows,
// 4 waves x 16 rows. Q,K split precision (3 terms); V plain bf16.
// ---------------------------------------------------------------------------
__global__ __launch_bounds__(256) void qkv_proj_kernel(
    const __bf16* __restrict__ xh, const __bf16* __restrict__ xl,
    const __bf16* __restrict__ wtq_h, const __bf16* __restrict__ wtq_l,
    const __bf16* __restrict__ wtk_h, const __bf16* __restrict__ wtk_l,
    const __bf16* __restrict__ wtv_h,
    __bf16* __restrict__ qh_o, __bf16* __restrict__ ql_o,
    __bf16* __restrict__ kh_o, __bf16* __restrict__ kl_o,
    __bf16* __restrict__ vt_o) {
    const int head = blockIdx.x / 64;
    const int rb = blockIdx.x % 64;
    const int wave = threadIdx.x >> 6;
    const int lane = threadIdx.x & 63;
    const int row0 = rb * 64 + wave * 16;
    const int lrow = lane & 15;
    const int lk8 = (lane >> 4) * 8;

    f32x4 accq[4], acck[4], accv[4];
#pragma unroll
    for (int f = 0; f < 4; ++f) {
        accq[f] = (f32x4){0.f, 0.f, 0.f, 0.f};
        acck[f] = (f32x4){0.f, 0.f, 0.f, 0.f};
        accv[f] = (f32x4){0.f, 0.f, 0.f, 0.f};
    }

    const __bf16* xh_row = xh + (size_t)(row0 + lrow) * E + lk8;
    const __bf16* xl_row = xl + (size_t)(row0 + lrow) * E + lk8;
    const __bf16* wq_h = wtq_h + head * DK * E;
    const __bf16* wq_l = wtq_l + head * DK * E;
    const __bf16* wk_h = wtk_h + head * DK * E;
    const __bf16* wk_l = wtk_l + head * DK * E;
    const __bf16* wv_h = wtv_h + head * DK * E;

    for (int ks = 0; ks < E / 32; ++ks) {
        bf16x8 a_h = *(const bf16x8*)(xh_row + ks * 32);
        bf16x8 a_l = *(const bf16x8*)(xl_row + ks * 32);
#pragma unroll
        for (int f = 0; f < 4; ++f) {
            int wo = (f * 16 + lrow) * E + ks * 32 + lk8;
            bf16x8 bqh = *(const bf16x8*)(wq_h + wo);
            bf16x8 bql = *(const bf16x8*)(wq_l + wo);
            bf16x8 bkh = *(const bf16x8*)(wk_h + wo);
            bf16x8 bkl = *(const bf16x8*)(wk_l + wo);
            bf16x8 bvh = *(const bf16x8*)(wv_h + wo);
            accq[f] = MFMA16(a_h, bqh, accq[f]);
            accq[f] = MFMA16(a_h, bql, accq[f]);
            accq[f] = MFMA16(a_l, bqh, accq[f]);
            acck[f] = MFMA16(a_h, bkh, acck[f]);
            acck[f] = MFMA16(a_h, bkl, acck[f]);
            acck[f] = MFMA16(a_l, bkh, acck[f]);
            accv[f] = MFMA16(a_h, bvh, accv[f]);
        }
    }

    // D layout: row = (lane>>4)*4 + r, col = f*16 + (lane&15)
#pragma unroll
    for (int f = 0; f < 4; ++f) {
#pragma unroll
        for (int r = 0; r < 4; ++r) {
            int srow = row0 + (lane >> 4) * 4 + r;
            int d = f * 16 + lrow;
            size_t qko = (size_t)head * SEQ * DK + (size_t)srow * DK + d;
            float qv = accq[f][r];
            __bf16 qhh = (__bf16)qv;
            qh_o[qko] = qhh;
            ql_o[qko] = (__bf16)(qv - (float)qhh);
            float kv = acck[f][r];
            __bf16 khh = (__bf16)kv;
            kh_o[qko] = khh;
            kl_o[qko] = (__bf16)(kv - (float)khh);
            vt_o[(size_t)head * DK * SEQ + (size_t)d * SEQ + srow] = (__bf16)accv[f][r];
        }
    }
}

// ---------------------------------------------------------------------------
// Kernel 3: causal flash attention.
// Block = 128 threads (2 waves), QB=64 q-rows (32/wave), KVB=64.
// K(hi,lo),V^T staged in LDS via global_load_lds, double-buffered,
// XOR-swizzled (inverse swizzle applied on the global source address).
// One __syncthreads per K-tile (2-phase template). Softmax via DPP ror16.
// ---------------------------------------------------------------------------
__global__ __launch_bounds__(128) void attn_kernel(
    const __bf16* __restrict__ qh, const __bf16* __restrict__ ql,
    const __bf16* __restrict__ kh, const __bf16* __restrict__ kl,
    const __bf16* __restrict__ vt,
    float* __restrict__ out) {
    __shared__ char kvlds[2][24576];  // [buf][ Kh 8K | Kl 8K | Vt 8K ]
    __shared__ char plds[2][4096];    // per-wave private P scratch (32x64 bf16)

    // XCD-chunked swizzle (768 = 8 XCDs x 96, bijective) + heavy-first
    const int wg = (blockIdx.x & 7) * 96 + (blockIdx.x >> 3);
    const int head = wg >> 6;
    const int qb = 63 - (wg & 63);
    const int q0 = qb * 64;
    const int wave = threadIdx.x >> 6;
    const int lane = threadIdx.x & 63;
    const int lrow = lane & 15;
    const int lk8 = (lane >> 4) * 8;
    const int g4 = (lane >> 4) * 4;

    const size_t hoff = (size_t)head * SEQ * DK;

    // Q fragments (hoisted): rows q0 + wave*32 + rt*16 + lrow
    bf16x8 qhf[2][2], qlf[2][2];
    {
        const __bf16* qp = qh + hoff + (size_t)(q0 + wave * 32 + lrow) * DK;
        const __bf16* lp = ql + hoff + (size_t)(q0 + wave * 32 + lrow) * DK;
#pragma unroll
        for (int rt = 0; rt < 2; ++rt)
#pragma unroll
            for (int ks = 0; ks < 2; ++ks) {
                qhf[rt][ks] = *(const bf16x8*)(qp + rt * 16 * DK + ks * 32 + lk8);
                qlf[rt][ks] = *(const bf16x8*)(lp + rt * 16 * DK + ks * 32 + lk8);
            }
    }

    const char* kh_b = (const char*)(kh + hoff);
    const char* kl_b = (const char*)(kl + hoff);
    const char* vt_b = (const char*)(vt + (size_t)head * DK * SEQ);

    const int slr = lane >> 3;        // row-within-chunk
    const int scb = (lane & 7) * 16;  // col byte

    f32x4 O[2][4];
    float m[2][4], l[2][4];
#pragma unroll
    for (int rt = 0; rt < 2; ++rt)
#pragma unroll
        for (int i = 0; i < 4; ++i) {
            O[rt][i] = (f32x4){0.f, 0.f, 0.f, 0.f};
            m[rt][i] = -3.0e38f;
            l[rt][i] = 0.f;
        }

    const int nt = qb + 1;

    // stage K-tile kb into kvlds[buf]; 24 x 1KB chunks, 12 per wave.
    // LDS dest is linear; the XOR swizzle is folded into the global source.
    auto STAGE = [&](int buf, int kb) {
        char* dst = kvlds[buf];
        const char* khs = kh_b + (size_t)kb * (DK * 2);
        const char* kls = kl_b + (size_t)kb * (DK * 2);
        const char* vts = vt_b + (size_t)kb * 2;
#pragma unroll
        for (int r = 0; r < 12; ++r) {
            int q = wave * 12 + r;
            int c = q & 7;
            int row = c * 8 + slr;
            int scol = scb ^ ((row & 7) << 4);
            const char* src;
            if (q < 8)       src = khs + row * 128 + scol;
            else if (q < 16) src = kls + row * 128 + scol;
            else             src = vts + (size_t)row * (SEQ * 2) + scol;
            gload16(src, dst + q * 1024);
        }
    };

    STAGE(0, 0);
    __syncthreads();
    int buf = 0;

    for (int t = 0; t < nt; ++t) {
        const int kb = t * 64;
        if (t + 1 < nt) STAGE(buf ^ 1, (t + 1) * 64);

        const char* Khl = kvlds[buf];
        const char* Kll = kvlds[buf] + 8192;
        const char* Vtl = kvlds[buf] + 16384;

        // ---- S = Q K^T (raw, unscaled; split 3-term) ----
        f32x4 sf[2][4];
#pragma unroll
        for (int f = 0; f < 4; ++f) {
            f32x4 a0 = (f32x4){0.f, 0.f, 0.f, 0.f};
            f32x4 a1 = (f32x4){0.f, 0.f, 0.f, 0.f};
#pragma unroll
            for (int ks = 0; ks < 2; ++ks) {
                int row = f * 16 + lrow;
                int off = row * 128 + (((ks * 32 + lk8) * 2) ^ ((row & 7) << 4));
                bf16x8 bh = *(const bf16x8*)(Khl + off);
                bf16x8 bl = *(const bf16x8*)(Kll + off);
                a0 = MFMA16(qhf[0][ks], bh, a0);
                a1 = MFMA16(qhf[1][ks], bh, a1);
                a0 = MFMA16(qhf[0][ks], bl, a0);
                a1 = MFMA16(qhf[1][ks], bl, a1);
                a0 = MFMA16(qlf[0][ks], bh, a0);
                a1 = MFMA16(qlf[1][ks], bh, a1);
            }
            sf[0][f] = a0;
            sf[1][f] = a1;
        }

        // ---- causal mask (diagonal tile only) ----
        if (t == nt - 1) {
#pragma unroll
            for (int rt = 0; rt < 2; ++rt)
#pragma unroll
                for (int f = 0; f < 4; ++f)
#pragma unroll
                    for (int r = 0; r < 4; ++r) {
                        int col = kb + f * 16 + lrow;
                        int row = q0 + wave * 32 + rt * 16 + g4 + r;
                        if (col > row) sf[rt][f][r] = -1.0e30f;
                    }
        }

        // ---- online softmax (fp32, raw max, 1/sqrt(dk) folded into exp2) ----
#pragma unroll
        for (int rt = 0; rt < 2; ++rt) {
            float alpha[4];
#pragma unroll
            for (int r = 0; r < 4; ++r) {
                float mx = fmaxf(fmaxf(sf[rt][0][r], sf[rt][1][r]),
                                 fmaxf(sf[rt][2][r], sf[rt][3][r]));
                mx = rmax16(mx);
                float mn = fmaxf(m[rt][r], mx);
                alpha[r] = exp2f((m[rt][r] - mn) * SCL);
                m[rt][r] = mn;
            }
#pragma unroll
            for (int f = 0; f < 4; ++f)
#pragma unroll
                for (int r = 0; r < 4; ++r)
                    sf[rt][f][r] = exp2f((sf[rt][f][r] - m[rt][r]) * SCL);
#pragma unroll
            for (int r = 0; r < 4; ++r) {
                float s = (sf[rt][0][r] + sf[rt][1][r]) + (sf[rt][2][r] + sf[rt][3][r]);
                s = rsum16(s);
                l[rt][r] = l[rt][r] * alpha[r] + s;
            }
#pragma unroll
            for (int df = 0; df < 4; ++df)
#pragma unroll
                for (int r = 0; r < 4; ++r)
                    O[rt][df][r] *= alpha[r];
        }

        // ---- P -> per-wave LDS (swizzled), then read back as A-fragments ----
        char* pw = plds[wave];
#pragma unroll
        for (int rt = 0; rt < 2; ++rt)
#pragma unroll
            for (int f = 0; f < 4; ++f)
#pragma unroll
                for (int r = 0; r < 4; ++r) {
                    int prow = rt * 16 + g4 + r;
                    int off = prow * 128 + (((f * 16 + lrow) * 2) ^ ((prow & 7) << 4));
                    *(__bf16*)(pw + off) = (__bf16)sf[rt][f][r];
                }
        bf16x8 pf[2][2];
#pragma unroll
        for (int rt = 0; rt < 2; ++rt)
#pragma unroll
            for (int ks = 0; ks < 2; ++ks) {
                int prow = rt * 16 + lrow;
                int off = prow * 128 + (((ks * 32 + lk8) * 2) ^ ((prow & 7) << 4));
                pf[rt][ks] = *(const bf16x8*)(pw + off);
            }

        // ---- O += P V ----
#pragma unroll
        for (int df = 0; df < 4; ++df) {
#pragma unroll
            for (int ks = 0; ks < 2; ++ks) {
                int d = df * 16 + lrow;
                int off = d * 128 + (((ks * 32 + lk8) * 2) ^ ((d & 7) << 4));
                bf16x8 vf = *(const bf16x8*)(Vtl + off);
                O[0][df] = MFMA16(pf[0][ks], vf, O[0][df]);
                O[1][df] = MFMA16(pf[1][ks], vf, O[1][df]);
            }
        }

        __syncthreads();  // drain stage DMA (vmcnt) + protect buf reuse
        buf ^= 1;
    }

    // ---- epilogue: out[h][s][d] = O / l ----
#pragma unroll
    for (int rt = 0; rt < 2; ++rt)
#pragma unroll
        for (int df = 0; df < 4; ++df)
#pragma unroll
            for (int r = 0; r < 4; ++r) {
                int row = q0 + wave * 32 + rt * 16 + g4 + r;
                out[hoff + (size_t)row * DK + df * 16 + lrow] = O[rt][df][r] / l[rt][r];
            }
}

// ---------------------------------------------------------------------------
extern "C" void kernel_launch(void* const* d_in, const int* in_sizes, int n_in,
                              void* d_out, int out_size, void* d_ws, size_t ws_size,
                              hipStream_t stream) {
    const float* x = (const float*)d_in[0];
    const float* qp = (const float*)d_in[1];
    const float* kp = (const float*)d_in[2];
    const float* vp = (const float*)d_in[3];
    float* out = (float*)d_out;

    const size_t WT_SZ = (size_t)NH * DK * E * 2;     // 1,179,648 B
    const size_t QKV_SZ = (size_t)NH * SEQ * DK * 2;  // 6,291,456 B
    const size_t X_SZ = (size_t)SEQ * E * 2;          // 6,291,456 B
    char* ws = (char*)d_ws;
    __bf16* wtq_h = (__bf16*)(ws + 0 * WT_SZ);
    __bf16* wtq_l = (__bf16*)(ws + 1 * WT_SZ);
    __bf16* wtk_h = (__bf16*)(ws + 2 * WT_SZ);
    __bf16* wtk_l = (__bf16*)(ws + 3 * WT_SZ);
    __bf16* wtv_h = (__bf16*)(ws + 4 * WT_SZ);
    char* p2 = ws + 5 * WT_SZ;
    __bf16* qh = (__bf16*)(p2 + 0 * QKV_SZ);
    __bf16* ql = (__bf16*)(p2 + 1 * QKV_SZ);
    __bf16* kh = (__bf16*)(p2 + 2 * QKV_SZ);
    __bf16* kl = (__bf16*)(p2 + 3 * QKV_SZ);
    __bf16* vt = (__bf16*)(p2 + 4 * QKV_SZ);
    char* p3 = p2 + 5 * QKV_SZ;
    __bf16* xh = (__bf16*)(p3 + 0 * X_SZ);
    __bf16* xl = (__bf16*)(p3 + 1 * X_SZ);
    // total ws use: ~47.6 MB

    hipLaunchKernelGGL(xsplit_kernel, dim3(SEQ * E / 4 / 256), dim3(256), 0, stream,
                       x, xh, xl);
    hipLaunchKernelGGL(wsplit_kernel, dim3((NH * E * DK + 255) / 256), dim3(256), 0, stream,
                       qp, kp, vp, wtq_h, wtq_l, wtk_h, wtk_l, wtv_h);
    hipLaunchKernelGGL(qkv_proj_kernel, dim3(NH * 64), dim3(256), 0, stream,
                       xh, xl, wtq_h, wtq_l, wtk_h, wtk_l, wtv_h, qh, ql, kh, kl, vt);
    hipLaunchKernelGGL(attn_kernel, dim3(NH * 64), dim3(128), 0, stream,
                       qh, ql, kh, kl, vt, out);
}

// Round 3
// 377.360 us; speedup vs baseline: 1.8761x; 1.0970x over previous
//
#include <hip/hip_runtime.h>
#include <hip/hip_bf16.h>

#define NH 12
#define SEQ 4096
#define E 768
#define DK 64

typedef float f32x4 __attribute__((ext_vector_type(4)));
typedef __bf16 bf16x8 __attribute__((ext_vector_type(8)));
typedef __bf16 bf16x4 __attribute__((ext_vector_type(4)));

#define MFMA16(a, b, c) __builtin_amdgcn_mfma_f32_16x16x32_bf16((a), (b), (c), 0, 0, 0)

// log2(e) / sqrt(dk) = 1.4426950408889634 / 8
#define SCL 0.18033688011112042f
// defer-max threshold (raw-score units): P bounded by 2^(60*SCL) ~= 2^10.8
#define DEFER 60.0f

// ---------------------------------------------------------------------------
// DPP rotate-reduce within 16-lane rows (no LDS traffic)
// ---------------------------------------------------------------------------
template <int N>
__device__ __forceinline__ float ror16(float x) {
    return __int_as_float(__builtin_amdgcn_update_dpp(
        0, __float_as_int(x), 0x120 | N, 0xf, 0xf, false));
}
__device__ __forceinline__ float rmax16(float v) {
    v = fmaxf(v, ror16<1>(v));
    v = fmaxf(v, ror16<2>(v));
    v = fmaxf(v, ror16<4>(v));
    v = fmaxf(v, ror16<8>(v));
    return v;
}
__device__ __forceinline__ float rsum16(float v) {
    v += ror16<1>(v);
    v += ror16<2>(v);
    v += ror16<4>(v);
    v += ror16<8>(v);
    return v;
}

__device__ __forceinline__ void gload16(const void* g, void* l) {
    __builtin_amdgcn_global_load_lds(
        (const __attribute__((address_space(1))) void*)g,
        (__attribute__((address_space(3))) void*)l, 16, 0, 0);
}

// ---------------------------------------------------------------------------
// Kernel 0: split x into bf16 hi/lo
// ---------------------------------------------------------------------------
__global__ __launch_bounds__(256) void xsplit_kernel(const float* __restrict__ x,
                                                     __bf16* __restrict__ xh,
                                                     __bf16* __restrict__ xl) {
    int i = blockIdx.x * blockDim.x + threadIdx.x;  // one float4 per thread
    float4 v = ((const float4*)x)[i];
    bf16x4 h, l;
    float vv[4] = {v.x, v.y, v.z, v.w};
#pragma unroll
    for (int j = 0; j < 4; ++j) {
        __bf16 hh = (__bf16)vv[j];
        h[j] = hh;
        l[j] = (__bf16)(vv[j] - (float)hh);
    }
    ((bf16x4*)xh)[i] = h;
    ((bf16x4*)xl)[i] = l;
}

// ---------------------------------------------------------------------------
// Kernel 1: split projection weights into bf16 hi/lo, transpose to [h][n][k]
// ---------------------------------------------------------------------------
__global__ void wsplit_kernel(const float* __restrict__ qp,
                              const float* __restrict__ kp,
                              const float* __restrict__ vp,
                              __bf16* __restrict__ wtq_h, __bf16* __restrict__ wtq_l,
                              __bf16* __restrict__ wtk_h, __bf16* __restrict__ wtk_l,
                              __bf16* __restrict__ wtv_h) {
    int idx = blockIdx.x * blockDim.x + threadIdx.x;
    if (idx >= NH * E * DK) return;
    int h = idx / (E * DK);
    int rem = idx - h * E * DK;
    int k = rem / DK;
    int n = rem - k * DK;
    int o = h * DK * E + n * E + k;  // [h][n][k]
    float q = qp[idx];
    __bf16 qh = (__bf16)q;
    wtq_h[o] = qh;
    wtq_l[o] = (__bf16)(q - (float)qh);
    float kk = kp[idx];
    __bf16 kh = (__bf16)kk;
    wtk_h[o] = kh;
    wtk_l[o] = (__bf16)(kk - (float)kh);
    wtv_h[o] = (__bf16)vp[idx];
}

// ---------------------------------------------------------------------------
// Kernel 2: fused QKV projection. Block = 1 head x 128 rows, 4 waves x 32 rows
// (2 row-fragments each). Q,K split precision (3 terms); V plain bf16 with
// swapped operands so V^T stores come out 32B-coalesced.
// XCD-chunked block swizzle keeps each head's weight set in one XCD's L2.
// ---------------------------------------------------------------------------
__global__ __launch_bounds__(256) void qkv_proj_kernel(
    const __bf16* __restrict__ xh, const __bf16* __restrict__ xl,
    const __bf16* __restrict__ wtq_h, const __bf16* __restrict__ wtq_l,
    const __bf16* __restrict__ wtk_h, const __bf16* __restrict__ wtk_l,
    const __bf16* __restrict__ wtv_h,
    __bf16* __restrict__ qh_o, __bf16* __restrict__ ql_o,
    __bf16* __restrict__ kh_o, __bf16* __restrict__ kl_o,
    __bf16* __restrict__ vt_o) {
    // 384 blocks = 8 XCDs x 48
    const int wg = (blockIdx.x & 7) * 48 + (blockIdx.x >> 3);
    const int head = wg >> 5;
    const int rb = wg & 31;
    const int wave = threadIdx.x >> 6;
    const int lane = threadIdx.x & 63;
    const int lrow = lane & 15;
    const int lk8 = (lane >> 4) * 8;
    const int g4 = (lane >> 4) * 4;
    const int rowbase = rb * 128 + wave * 32;

    f32x4 accq[2][4], acck[2][4], accv[2][4];
#pragma unroll
    for (int rt = 0; rt < 2; ++rt)
#pragma unroll
        for (int f = 0; f < 4; ++f) {
            accq[rt][f] = (f32x4){0.f, 0.f, 0.f, 0.f};
            acck[rt][f] = (f32x4){0.f, 0.f, 0.f, 0.f};
            accv[rt][f] = (f32x4){0.f, 0.f, 0.f, 0.f};
        }

    const __bf16* wq_h = wtq_h + head * DK * E;
    const __bf16* wq_l = wtq_l + head * DK * E;
    const __bf16* wk_h = wtk_h + head * DK * E;
    const __bf16* wk_l = wtk_l + head * DK * E;
    const __bf16* wv_h = wtv_h + head * DK * E;

    for (int ks = 0; ks < E / 32; ++ks) {
        bf16x8 ah[2], al[2];
#pragma unroll
        for (int rt = 0; rt < 2; ++rt) {
            size_t xo = (size_t)(rowbase + rt * 16 + lrow) * E + ks * 32 + lk8;
            ah[rt] = *(const bf16x8*)(xh + xo);
            al[rt] = *(const bf16x8*)(xl + xo);
        }
#pragma unroll
        for (int f = 0; f < 4; ++f) {
            int wo = (f * 16 + lrow) * E + ks * 32 + lk8;
            bf16x8 bqh = *(const bf16x8*)(wq_h + wo);
            bf16x8 bql = *(const bf16x8*)(wq_l + wo);
            bf16x8 bkh = *(const bf16x8*)(wk_h + wo);
            bf16x8 bkl = *(const bf16x8*)(wk_l + wo);
            bf16x8 bvh = *(const bf16x8*)(wv_h + wo);
#pragma unroll
            for (int rt = 0; rt < 2; ++rt) {
                accq[rt][f] = MFMA16(ah[rt], bqh, accq[rt][f]);
                accq[rt][f] = MFMA16(ah[rt], bql, accq[rt][f]);
                accq[rt][f] = MFMA16(al[rt], bqh, accq[rt][f]);
                acck[rt][f] = MFMA16(ah[rt], bkh, acck[rt][f]);
                acck[rt][f] = MFMA16(ah[rt], bkl, acck[rt][f]);
                acck[rt][f] = MFMA16(al[rt], bkh, acck[rt][f]);
                // swapped: D[d][s] for coalesced V^T store
                accv[rt][f] = MFMA16(bvh, ah[rt], accv[rt][f]);
            }
        }
    }

#pragma unroll
    for (int rt = 0; rt < 2; ++rt)
#pragma unroll
        for (int f = 0; f < 4; ++f) {
#pragma unroll
            for (int r = 0; r < 4; ++r) {
                // Q/K: D[s][n] -> row = g4+r, col = lrow
                int srow = rowbase + rt * 16 + g4 + r;
                int d = f * 16 + lrow;
                size_t qko = (size_t)head * SEQ * DK + (size_t)srow * DK + d;
                float qv = accq[rt][f][r];
                __bf16 qhh = (__bf16)qv;
                qh_o[qko] = qhh;
                ql_o[qko] = (__bf16)(qv - (float)qhh);
                float kv = acck[rt][f][r];
                __bf16 khh = (__bf16)kv;
                kh_o[qko] = khh;
                kl_o[qko] = (__bf16)(kv - (float)khh);
                // V: D[d][s] -> row = d (g4+r), col = s (lrow)
                int vd = f * 16 + g4 + r;
                int vs = rowbase + rt * 16 + lrow;
                vt_o[(size_t)head * DK * SEQ + (size_t)vd * SEQ + vs] = (__bf16)accv[rt][f][r];
            }
        }
}

// ---------------------------------------------------------------------------
// Kernel 3: causal flash attention.
// Block = 256 threads (4 waves), QB=128 q-rows (32/wave), KVB=64.
// K(hi,lo),V^T staged in LDS via global_load_lds, double-buffered, XOR-swizzled
// (inverse swizzle folded into the global source). One __syncthreads per tile.
// Softmax via DPP ror16; defer-max skips O-rescale on most tiles.
// ---------------------------------------------------------------------------
__global__ __launch_bounds__(256) void attn_kernel(
    const __bf16* __restrict__ qh, const __bf16* __restrict__ ql,
    const __bf16* __restrict__ kh, const __bf16* __restrict__ kl,
    const __bf16* __restrict__ vt,
    float* __restrict__ out) {
    __shared__ char kvlds[2][24576];  // [buf][ Kh 8K | Kl 8K | Vt 8K ]
    __shared__ char plds[4][4096];    // per-wave P scratch (32x64 bf16, swizzled)

    // 384 blocks = 8 XCDs x 48 (bijective) + heavy-first
    const int wg = (blockIdx.x & 7) * 48 + (blockIdx.x >> 3);
    const int head = wg >> 5;
    const int qb = 31 - (wg & 31);
    const int q0 = qb * 128;
    const int wave = threadIdx.x >> 6;
    const int lane = threadIdx.x & 63;
    const int lrow = lane & 15;
    const int lk8 = (lane >> 4) * 8;
    const int g4 = (lane >> 4) * 4;

    const size_t hoff = (size_t)head * SEQ * DK;
    const int rowbase = q0 + wave * 32;

    // Q fragments (hoisted)
    bf16x8 qhf[2][2], qlf[2][2];
    {
        const __bf16* qp = qh + hoff + (size_t)(rowbase + lrow) * DK;
        const __bf16* lp = ql + hoff + (size_t)(rowbase + lrow) * DK;
#pragma unroll
        for (int rt = 0; rt < 2; ++rt)
#pragma unroll
            for (int ks = 0; ks < 2; ++ks) {
                qhf[rt][ks] = *(const bf16x8*)(qp + rt * 16 * DK + ks * 32 + lk8);
                qlf[rt][ks] = *(const bf16x8*)(lp + rt * 16 * DK + ks * 32 + lk8);
            }
    }

    const char* kh_b = (const char*)(kh + hoff);
    const char* kl_b = (const char*)(kl + hoff);
    const char* vt_b = (const char*)(vt + (size_t)head * DK * SEQ);

    const int slr = lane >> 3;        // row-within-chunk
    const int scb = (lane & 7) * 16;  // col byte

    f32x4 O[2][4];
    float m[2][4], l[2][4];
#pragma unroll
    for (int rt = 0; rt < 2; ++rt)
#pragma unroll
        for (int i = 0; i < 4; ++i) {
            O[rt][i] = (f32x4){0.f, 0.f, 0.f, 0.f};
            m[rt][i] = -3.0e38f;
            l[rt][i] = 0.f;
        }

    const int nt = 2 * qb + 2;

    // stage one 64-row K/V tile: 24 x 1KB chunks, 6 per wave.
    auto STAGE = [&](int buf, int kb) {
        char* dst = kvlds[buf];
        const char* khs = kh_b + (size_t)kb * (DK * 2);
        const char* kls = kl_b + (size_t)kb * (DK * 2);
        const char* vts = vt_b + (size_t)kb * 2;
#pragma unroll
        for (int r = 0; r < 6; ++r) {
            int q = r * 4 + wave;
            int c = q & 7;
            int row = c * 8 + slr;
            int scol = scb ^ ((row & 7) << 4);
            const char* src;
            if (q < 8)       src = khs + row * 128 + scol;
            else if (q < 16) src = kls + row * 128 + scol;
            else             src = vts + (size_t)row * (SEQ * 2) + scol;
            gload16(src, dst + q * 1024);
        }
    };

    STAGE(0, 0);
    __syncthreads();
    int buf = 0;

    for (int t = 0; t < nt; ++t) {
        const int kb = t * 64;
        if (t + 1 < nt) STAGE(buf ^ 1, (t + 1) * 64);

        const char* Khl = kvlds[buf];
        const char* Kll = kvlds[buf] + 8192;
        const char* Vtl = kvlds[buf] + 16384;

        // ---- S = Q K^T (raw, unscaled; split 3-term) ----
        f32x4 sf[2][4];
#pragma unroll
        for (int f = 0; f < 4; ++f) {
            f32x4 a0 = (f32x4){0.f, 0.f, 0.f, 0.f};
            f32x4 a1 = (f32x4){0.f, 0.f, 0.f, 0.f};
#pragma unroll
            for (int ks = 0; ks < 2; ++ks) {
                int row = f * 16 + lrow;
                int off = row * 128 + (((ks * 32 + lk8) * 2) ^ ((row & 7) << 4));
                bf16x8 bh = *(const bf16x8*)(Khl + off);
                bf16x8 bl = *(const bf16x8*)(Kll + off);
                a0 = MFMA16(qhf[0][ks], bh, a0);
                a1 = MFMA16(qhf[1][ks], bh, a1);
                a0 = MFMA16(qhf[0][ks], bl, a0);
                a1 = MFMA16(qhf[1][ks], bl, a1);
                a0 = MFMA16(qlf[0][ks], bh, a0);
                a1 = MFMA16(qlf[1][ks], bh, a1);
            }
            sf[0][f] = a0;
            sf[1][f] = a1;
        }

        // ---- causal mask (any tile at/past this wave's diagonal) ----
        if (kb + 63 > rowbase) {
#pragma unroll
            for (int rt = 0; rt < 2; ++rt)
#pragma unroll
                for (int f = 0; f < 4; ++f)
#pragma unroll
                    for (int r = 0; r < 4; ++r) {
                        int col = kb + f * 16 + lrow;
                        int row = rowbase + rt * 16 + g4 + r;
                        if (col > row) sf[rt][f][r] = -1.0e30f;
                    }
        }

        // ---- online softmax with defer-max ----
#pragma unroll
        for (int rt = 0; rt < 2; ++rt) {
            float mx[4];
#pragma unroll
            for (int r = 0; r < 4; ++r) {
                float v = fmaxf(fmaxf(sf[rt][0][r], sf[rt][1][r]),
                                fmaxf(sf[rt][2][r], sf[rt][3][r]));
                mx[r] = rmax16(v);
            }
            int small = (mx[0] - m[rt][0] <= DEFER) & (mx[1] - m[rt][1] <= DEFER) &
                        (mx[2] - m[rt][2] <= DEFER) & (mx[3] - m[rt][3] <= DEFER);
            if (!__all(small)) {
#pragma unroll
                for (int r = 0; r < 4; ++r) {
                    float mn = fmaxf(m[rt][r], mx[r]);
                    float alpha = exp2f((m[rt][r] - mn) * SCL);
                    m[rt][r] = mn;
                    l[rt][r] *= alpha;
#pragma unroll
                    for (int df = 0; df < 4; ++df) O[rt][df][r] *= alpha;
                }
            }
#pragma unroll
            for (int f = 0; f < 4; ++f)
#pragma unroll
                for (int r = 0; r < 4; ++r)
                    sf[rt][f][r] = exp2f((sf[rt][f][r] - m[rt][r]) * SCL);
#pragma unroll
            for (int r = 0; r < 4; ++r) {
                float s = (sf[rt][0][r] + sf[rt][1][r]) + (sf[rt][2][r] + sf[rt][3][r]);
                l[rt][r] += rsum16(s);
            }
        }

        // ---- P -> per-wave LDS (swizzled), read back as A-fragments ----
        char* pw = plds[wave];
#pragma unroll
        for (int rt = 0; rt < 2; ++rt)
#pragma unroll
            for (int f = 0; f < 4; ++f)
#pragma unroll
                for (int r = 0; r < 4; ++r) {
                    int prow = rt * 16 + g4 + r;
                    int off = prow * 128 + (((f * 16 + lrow) * 2) ^ ((prow & 7) << 4));
                    *(__bf16*)(pw + off) = (__bf16)sf[rt][f][r];
                }
        bf16x8 pf[2][2];
#pragma unroll
        for (int rt = 0; rt < 2; ++rt)
#pragma unroll
            for (int ks = 0; ks < 2; ++ks) {
                int prow = rt * 16 + lrow;
                int off = prow * 128 + (((ks * 32 + lk8) * 2) ^ ((prow & 7) << 4));
                pf[rt][ks] = *(const bf16x8*)(pw + off);
            }

        // ---- O += P V ----
#pragma unroll
        for (int df = 0; df < 4; ++df) {
#pragma unroll
            for (int ks = 0; ks < 2; ++ks) {
                int d = df * 16 + lrow;
                int off = d * 128 + (((ks * 32 + lk8) * 2) ^ ((d & 7) << 4));
                bf16x8 vf = *(const bf16x8*)(Vtl + off);
                O[0][df] = MFMA16(pf[0][ks], vf, O[0][df]);
                O[1][df] = MFMA16(pf[1][ks], vf, O[1][df]);
            }
        }

        __syncthreads();  // drain stage DMA + protect buf reuse
        buf ^= 1;
    }

    // ---- epilogue: out[h][s][d] = O / l ----
#pragma unroll
    for (int rt = 0; rt < 2; ++rt)
#pragma unroll
        for (int df = 0; df < 4; ++df)
#pragma unroll
            for (int r = 0; r < 4; ++r) {
                int row = rowbase + rt * 16 + g4 + r;
                out[hoff + (size_t)row * DK + df * 16 + lrow] = O[rt][df][r] / l[rt][r];
            }
}

// ---------------------------------------------------------------------------
extern "C" void kernel_launch(void* const* d_in, const int* in_sizes, int n_in,
                              void* d_out, int out_size, void* d_ws, size_t ws_size,
                              hipStream_t stream) {
    const float* x = (const float*)d_in[0];
    const float* qp = (const float*)d_in[1];
    const float* kp = (const float*)d_in[2];
    const float* vp = (const float*)d_in[3];
    float* out = (float*)d_out;

    const size_t WT_SZ = (size_t)NH * DK * E * 2;     // 1,179,648 B
    const size_t QKV_SZ = (size_t)NH * SEQ * DK * 2;  // 6,291,456 B
    const size_t X_SZ = (size_t)SEQ * E * 2;          // 6,291,456 B
    char* ws = (char*)d_ws;
    __bf16* wtq_h = (__bf16*)(ws + 0 * WT_SZ);
    __bf16* wtq_l = (__bf16*)(ws + 1 * WT_SZ);
    __bf16* wtk_h = (__bf16*)(ws + 2 * WT_SZ);
    __bf16* wtk_l = (__bf16*)(ws + 3 * WT_SZ);
    __bf16* wtv_h = (__bf16*)(ws + 4 * WT_SZ);
    char* p2 = ws + 5 * WT_SZ;
    __bf16* qh = (__bf16*)(p2 + 0 * QKV_SZ);
    __bf16* ql = (__bf16*)(p2 + 1 * QKV_SZ);
    __bf16* kh = (__bf16*)(p2 + 2 * QKV_SZ);
    __bf16* kl = (__bf16*)(p2 + 3 * QKV_SZ);
    __bf16* vt = (__bf16*)(p2 + 4 * QKV_SZ);
    char* p3 = p2 + 5 * QKV_SZ;
    __bf16* xh = (__bf16*)(p3 + 0 * X_SZ);
    __bf16* xl = (__bf16*)(p3 + 1 * X_SZ);

    hipLaunchKernelGGL(xsplit_kernel, dim3(SEQ * E / 4 / 256), dim3(256), 0, stream,
                       x, xh, xl);
    hipLaunchKernelGGL(wsplit_kernel, dim3((NH * E * DK + 255) / 256), dim3(256), 0, stream,
                       qp, kp, vp, wtq_h, wtq_l, wtk_h, wtk_l, wtv_h);
    hipLaunchKernelGGL(qkv_proj_kernel, dim3(384), dim3(256), 0, stream,
                       xh, xl, wtq_h, wtq_l, wtk_h, wtk_l, wtv_h, qh, ql, kh, kl, vt);
    hipLaunchKernelGGL(attn_kernel, dim3(384), dim3(256), 0, stream,
                       qh, ql, kh, kl, vt, out);
}

// Round 4
// 314.200 us; speedup vs baseline: 2.2532x; 1.2010x over previous
//
#include <hip/hip_runtime.h>
#include <hip/hip_bf16.h>

#define NH 12
#define SEQ 4096
#define E 768
#define DK 64

typedef float f32x4 __attribute__((ext_vector_type(4)));
typedef __bf16 bf16x8 __attribute__((ext_vector_type(8)));
typedef __bf16 bf16x4 __attribute__((ext_vector_type(4)));

#define MFMA16(a, b, c) __builtin_amdgcn_mfma_f32_16x16x32_bf16((a), (b), (c), 0, 0, 0)

// log2(e) / sqrt(dk); folded into K at wsplit time.
#define SCL 0.18033688011112042f
// defer-max threshold in scaled (log2) units: P bounded by 2^10.8
#define DEFER 10.8f

// ---------------------------------------------------------------------------
template <int N>
__device__ __forceinline__ float ror16(float x) {
    return __int_as_float(__builtin_amdgcn_update_dpp(
        0, __float_as_int(x), 0x120 | N, 0xf, 0xf, false));
}
__device__ __forceinline__ float rmax16(float v) {
    v = fmaxf(v, ror16<1>(v));
    v = fmaxf(v, ror16<2>(v));
    v = fmaxf(v, ror16<4>(v));
    v = fmaxf(v, ror16<8>(v));
    return v;
}

__device__ __forceinline__ void gload16(const void* g, void* l) {
    __builtin_amdgcn_global_load_lds(
        (const __attribute__((address_space(1))) void*)g,
        (__attribute__((address_space(3))) void*)l, 16, 0, 0);
}

__device__ __forceinline__ void block_sync() {
    __builtin_amdgcn_sched_barrier(0);
    __builtin_amdgcn_s_barrier();
    __builtin_amdgcn_sched_barrier(0);
}

// ---------------------------------------------------------------------------
// Kernel 0: split x into bf16 hi/lo
// ---------------------------------------------------------------------------
__global__ __launch_bounds__(256) void xsplit_kernel(const float* __restrict__ x,
                                                     __bf16* __restrict__ xh,
                                                     __bf16* __restrict__ xl) {
    int i = blockIdx.x * blockDim.x + threadIdx.x;
    float4 v = ((const float4*)x)[i];
    bf16x4 h, l;
    float vv[4] = {v.x, v.y, v.z, v.w};
#pragma unroll
    for (int j = 0; j < 4; ++j) {
        __bf16 hh = (__bf16)vv[j];
        h[j] = hh;
        l[j] = (__bf16)(vv[j] - (float)hh);
    }
    ((bf16x4*)xh)[i] = h;
    ((bf16x4*)xl)[i] = l;
}

// ---------------------------------------------------------------------------
// Kernel 1: split projection weights (hi/lo), transpose to [h][n][k].
// K weights are pre-scaled by SCL so attention scores come out in log2 units.
// ---------------------------------------------------------------------------
__global__ void wsplit_kernel(const float* __restrict__ qp,
                              const float* __restrict__ kp,
                              const float* __restrict__ vp,
                              __bf16* __restrict__ wtq_h, __bf16* __restrict__ wtq_l,
                              __bf16* __restrict__ wtk_h, __bf16* __restrict__ wtk_l,
                              __bf16* __restrict__ wtv_h) {
    int idx = blockIdx.x * blockDim.x + threadIdx.x;
    if (idx >= NH * E * DK) return;
    int h = idx / (E * DK);
    int rem = idx - h * E * DK;
    int k = rem / DK;
    int n = rem - k * DK;
    int o = h * DK * E + n * E + k;  // [h][n][k]
    float q = qp[idx];
    __bf16 qh = (__bf16)q;
    wtq_h[o] = qh;
    wtq_l[o] = (__bf16)(q - (float)qh);
    float kk = kp[idx] * SCL;
    __bf16 kh = (__bf16)kk;
    wtk_h[o] = kh;
    wtk_l[o] = (__bf16)(kk - (float)kh);
    wtv_h[o] = (__bf16)vp[idx];
}

// ---------------------------------------------------------------------------
// Kernel 2a: Q or K projection. Block = 256 rows x 1 head, 4 waves x 64 rows.
// Weights (hi+lo) staged in LDS via global_load_lds, double-buffered, counted
// vmcnt. 3-term split-precision MFMA. Outputs hi/lo bf16 [h][s][d].
// ---------------------------------------------------------------------------
__global__ __launch_bounds__(256) void proj_qk_kernel(
    const __bf16* __restrict__ xh, const __bf16* __restrict__ xl,
    const __bf16* __restrict__ w_h, const __bf16* __restrict__ w_l,
    __bf16* __restrict__ o_h, __bf16* __restrict__ o_l) {
    __shared__ char wlds[2][8192];  // [buf][ Wh 4K | Wl 4K ]

    const int wg = (blockIdx.x & 7) * 24 + (blockIdx.x >> 3);  // 192 = 8 x 24
    const int head = wg % NH;
    const int rb = wg / NH;  // 0..15
    const int wave = threadIdx.x >> 6;
    const int lane = threadIdx.x & 63;
    const int lrow = lane & 15;
    const int lk8 = (lane >> 4) * 8;
    const int g4 = (lane >> 4) * 4;
    const int rowbase = rb * 256 + wave * 64;

    const char* wh_b = (const char*)(w_h + head * DK * E);
    const char* wl_b = (const char*)(w_l + head * DK * E);
    const int srow = lane >> 2;        // 0..15
    const int scol = (lane & 3) * 16;  // byte in 64B row-slice

    // stage 8KB (2 mats x 4 chunks of 1KB); 2 chunks per wave
    auto STAGE = [&](int buf, int ks) {
#pragma unroll
        for (int r = 0; r < 2; ++r) {
            int q = wave * 2 + r;  // 0..7
            const char* base = (q >> 2) ? wl_b : wh_b;
            const char* src = base + (size_t)((q & 3) * 16 + srow) * (E * 2) + ks * 64 + scol;
            gload16(src, wlds[buf] + q * 1024 + lane * 16);
        }
    };

    f32x4 acc[4][4];
#pragma unroll
    for (int rt = 0; rt < 4; ++rt)
#pragma unroll
        for (int f = 0; f < 4; ++f) acc[rt][f] = (f32x4){0.f, 0.f, 0.f, 0.f};

    bf16x8 ah[4], al[4], ahn[4], aln[4];
    auto LOADA = [&](int ks, bf16x8* h, bf16x8* l) {
#pragma unroll
        for (int rt = 0; rt < 4; ++rt) {
            size_t xo = (size_t)(rowbase + rt * 16 + lrow) * E + ks * 32 + lk8;
            h[rt] = *(const bf16x8*)(xh + xo);
            l[rt] = *(const bf16x8*)(xl + xo);
        }
    };

    LOADA(0, ah, al);
    STAGE(0, 0);
    int buf = 0;
    for (int ks = 0; ks < 24; ++ks) {
        if (ks < 23) {
            LOADA(ks + 1, ahn, aln);
            STAGE(buf ^ 1, ks + 1);
            asm volatile("s_waitcnt vmcnt(10)" ::: "memory");
        } else {
            asm volatile("s_waitcnt vmcnt(0)" ::: "memory");
        }
        block_sync();
#pragma unroll
        for (int f = 0; f < 4; ++f) {
            int bo = (f * 16 + lrow) * 64 + lk8 * 2;
            bf16x8 bh = *(const bf16x8*)(wlds[buf] + bo);
            bf16x8 bl = *(const bf16x8*)(wlds[buf] + 4096 + bo);
#pragma unroll
            for (int rt = 0; rt < 4; ++rt) {
                acc[rt][f] = MFMA16(ah[rt], bh, acc[rt][f]);
                acc[rt][f] = MFMA16(ah[rt], bl, acc[rt][f]);
                acc[rt][f] = MFMA16(al[rt], bh, acc[rt][f]);
            }
        }
        block_sync();
        if (ks < 23) {
#pragma unroll
            for (int rt = 0; rt < 4; ++rt) {
                ah[rt] = ahn[rt];
                al[rt] = aln[rt];
            }
        }
        buf ^= 1;
    }

#pragma unroll
    for (int rt = 0; rt < 4; ++rt)
#pragma unroll
        for (int f = 0; f < 4; ++f)
#pragma unroll
            for (int r = 0; r < 4; ++r) {
                int srow_o = rowbase + rt * 16 + g4 + r;
                int d = f * 16 + lrow;
                size_t o = (size_t)head * SEQ * DK + (size_t)srow_o * DK + d;
                float v = acc[rt][f][r];
                __bf16 hh = (__bf16)v;
                o_h[o] = hh;
                o_l[o] = (__bf16)(v - (float)hh);
            }
}

// ---------------------------------------------------------------------------
// Kernel 2b: V projection (1-term, operand-swapped so V^T stores coalesce).
// ---------------------------------------------------------------------------
__global__ __launch_bounds__(256) void proj_v_kernel(
    const __bf16* __restrict__ xh, const __bf16* __restrict__ w_v,
    __bf16* __restrict__ vt_o) {
    __shared__ char wlds[2][4096];

    const int wg = (blockIdx.x & 7) * 24 + (blockIdx.x >> 3);
    const int head = wg % NH;
    const int rb = wg / NH;
    const int wave = threadIdx.x >> 6;
    const int lane = threadIdx.x & 63;
    const int lrow = lane & 15;
    const int lk8 = (lane >> 4) * 8;
    const int g4 = (lane >> 4) * 4;
    const int rowbase = rb * 256 + wave * 64;

    const char* wv_b = (const char*)(w_v + head * DK * E);
    const int srow = lane >> 2;
    const int scol = (lane & 3) * 16;

    auto STAGE = [&](int buf, int ks) {
        const char* src = wv_b + (size_t)(wave * 16 + srow) * (E * 2) + ks * 64 + scol;
        gload16(src, wlds[buf] + wave * 1024 + lane * 16);
    };

    f32x4 acc[4][4];
#pragma unroll
    for (int rt = 0; rt < 4; ++rt)
#pragma unroll
        for (int f = 0; f < 4; ++f) acc[rt][f] = (f32x4){0.f, 0.f, 0.f, 0.f};

    bf16x8 ah[4], ahn[4];
    auto LOADA = [&](int ks, bf16x8* h) {
#pragma unroll
        for (int rt = 0; rt < 4; ++rt) {
            size_t xo = (size_t)(rowbase + rt * 16 + lrow) * E + ks * 32 + lk8;
            h[rt] = *(const bf16x8*)(xh + xo);
        }
    };

    LOADA(0, ah);
    STAGE(0, 0);
    int buf = 0;
    for (int ks = 0; ks < 24; ++ks) {
        if (ks < 23) {
            LOADA(ks + 1, ahn);
            STAGE(buf ^ 1, ks + 1);
            asm volatile("s_waitcnt vmcnt(5)" ::: "memory");
        } else {
            asm volatile("s_waitcnt vmcnt(0)" ::: "memory");
        }
        block_sync();
#pragma unroll
        for (int f = 0; f < 4; ++f) {
            int bo = (f * 16 + lrow) * 64 + lk8 * 2;
            bf16x8 bv = *(const bf16x8*)(wlds[buf] + bo);
#pragma unroll
            for (int rt = 0; rt < 4; ++rt)
                acc[rt][f] = MFMA16(bv, ah[rt], acc[rt][f]);  // D[d][s]
        }
        block_sync();
        if (ks < 23) {
#pragma unroll
            for (int rt = 0; rt < 4; ++rt) ah[rt] = ahn[rt];
        }
        buf ^= 1;
    }

#pragma unroll
    for (int rt = 0; rt < 4; ++rt)
#pragma unroll
        for (int f = 0; f < 4; ++f)
#pragma unroll
            for (int r = 0; r < 4; ++r) {
                int vd = f * 16 + g4 + r;
                int vs = rowbase + rt * 16 + lrow;
                vt_o[(size_t)head * DK * SEQ + (size_t)vd * SEQ + vs] = (__bf16)acc[rt][f][r];
            }
}

// ---------------------------------------------------------------------------
// Kernel 3: causal flash attention.
// 4 waves x 32 q-rows (QB=128), KVB=64. K(hi,lo),V^T staged via global_load_lds
// (dbuf, XOR-swizzled via pre-swizzled source). Counted-vmcnt pipeline: two raw
// s_barriers per tile, vmcnt(6) mid-loop (never drains prefetch). l-sum via
// MFMA-with-ones (lands in accumulator layout). K pre-scaled -> exp2(s - m).
// ---------------------------------------------------------------------------
__global__ __launch_bounds__(256) void attn_kernel(
    const __bf16* __restrict__ qh, const __bf16* __restrict__ ql,
    const __bf16* __restrict__ kh, const __bf16* __restrict__ kl,
    const __bf16* __restrict__ vt,
    float* __restrict__ out) {
    __shared__ char kvlds[2][24576];  // [buf][ Kh 8K | Kl 8K | Vt 8K ]
    __shared__ char plds[4][4096];    // per-wave P scratch (32x64 bf16, swizzled)

    const int wg = (blockIdx.x & 7) * 48 + (blockIdx.x >> 3);  // 384 = 8 x 48
    const int head = wg >> 5;
    const int qb = 31 - (wg & 31);  // heavy-first
    const int q0 = qb * 128;
    const int wave = threadIdx.x >> 6;
    const int lane = threadIdx.x & 63;
    const int lrow = lane & 15;
    const int lk8 = (lane >> 4) * 8;
    const int g4 = (lane >> 4) * 4;

    const size_t hoff = (size_t)head * SEQ * DK;
    const int rowbase = q0 + wave * 32;

    // Q fragments (hoisted)
    bf16x8 qhf[2][2], qlf[2][2];
    {
        const __bf16* qp = qh + hoff + (size_t)(rowbase + lrow) * DK;
        const __bf16* lp = ql + hoff + (size_t)(rowbase + lrow) * DK;
#pragma unroll
        for (int rt = 0; rt < 2; ++rt)
#pragma unroll
            for (int ks = 0; ks < 2; ++ks) {
                qhf[rt][ks] = *(const bf16x8*)(qp + rt * 16 * DK + ks * 32 + lk8);
                qlf[rt][ks] = *(const bf16x8*)(lp + rt * 16 * DK + ks * 32 + lk8);
            }
    }
    asm volatile("s_waitcnt vmcnt(0)" ::: "memory");  // clean vmcnt baseline

    const char* kh_b = (const char*)(kh + hoff);
    const char* kl_b = (const char*)(kl + hoff);
    const char* vt_b = (const char*)(vt + (size_t)head * DK * SEQ);

    const int slr = lane >> 3;
    const int scb = (lane & 7) * 16;

    bf16x8 ones;
#pragma unroll
    for (int j = 0; j < 8; ++j) ones[j] = (__bf16)1.0f;

    f32x4 O[2][4], lacc[2];
    float m[2][4];
#pragma unroll
    for (int rt = 0; rt < 2; ++rt) {
        lacc[rt] = (f32x4){0.f, 0.f, 0.f, 0.f};
#pragma unroll
        for (int i = 0; i < 4; ++i) {
            O[rt][i] = (f32x4){0.f, 0.f, 0.f, 0.f};
            m[rt][i] = -3.0e38f;
        }
    }

    const int nt = 2 * qb + 2;

    auto STAGE = [&](int buf, int kb) {
        char* dst = kvlds[buf];
        const char* khs = kh_b + (size_t)kb * (DK * 2);
        const char* kls = kl_b + (size_t)kb * (DK * 2);
        const char* vts = vt_b + (size_t)kb * 2;
#pragma unroll
        for (int r = 0; r < 6; ++r) {
            int q = r * 4 + wave;
            int c = q & 7;
            int row = c * 8 + slr;
            int scol = scb ^ ((row & 7) << 4);
            const char* src;
            if (q < 8)       src = khs + row * 128 + scol;
            else if (q < 16) src = kls + row * 128 + scol;
            else             src = vts + (size_t)row * (SEQ * 2) + scol;
            gload16(src, dst + q * 1024);
        }
    };

    STAGE(0, 0);
    int buf = 0;

    for (int t = 0; t < nt; ++t) {
        const int kb = t * 64;
        if (t + 1 < nt) {
            STAGE(buf ^ 1, (t + 1) * 64);
            asm volatile("s_waitcnt vmcnt(6)" ::: "memory");  // tile-t DMA landed
        } else {
            asm volatile("s_waitcnt vmcnt(0)" ::: "memory");
        }
        block_sync();  // barrier A: all waves' tile-t data in LDS

        const char* Khl = kvlds[buf];
        const char* Kll = kvlds[buf] + 8192;
        const char* Vtl = kvlds[buf] + 16384;

        // ---- S = Q K'^T (already in log2 units) ----
        f32x4 sf[2][4];
#pragma unroll
        for (int f = 0; f < 4; ++f) {
            f32x4 a0 = (f32x4){0.f, 0.f, 0.f, 0.f};
            f32x4 a1 = (f32x4){0.f, 0.f, 0.f, 0.f};
#pragma unroll
            for (int ks = 0; ks < 2; ++ks) {
                int row = f * 16 + lrow;
                int off = row * 128 + (((ks * 32 + lk8) * 2) ^ ((row & 7) << 4));
                bf16x8 bh = *(const bf16x8*)(Khl + off);
                bf16x8 bl = *(const bf16x8*)(Kll + off);
                a0 = MFMA16(qhf[0][ks], bh, a0);
                a1 = MFMA16(qhf[1][ks], bh, a1);
                a0 = MFMA16(qhf[0][ks], bl, a0);
                a1 = MFMA16(qhf[1][ks], bl, a1);
                a0 = MFMA16(qlf[0][ks], bh, a0);
                a1 = MFMA16(qlf[1][ks], bh, a1);
            }
            sf[0][f] = a0;
            sf[1][f] = a1;
        }

        // ---- causal mask ----
        if (kb + 63 > rowbase) {
#pragma unroll
            for (int rt = 0; rt < 2; ++rt)
#pragma unroll
                for (int f = 0; f < 4; ++f)
#pragma unroll
                    for (int r = 0; r < 4; ++r) {
                        int col = kb + f * 16 + lrow;
                        int row = rowbase + rt * 16 + g4 + r;
                        if (col > row) sf[rt][f][r] = -1.0e30f;
                    }
        }

        // ---- online softmax with defer-max; l via MFMA-ones ----
#pragma unroll
        for (int rt = 0; rt < 2; ++rt) {
            float mx[4];
#pragma unroll
            for (int r = 0; r < 4; ++r) {
                float v = fmaxf(fmaxf(sf[rt][0][r], sf[rt][1][r]),
                                fmaxf(sf[rt][2][r], sf[rt][3][r]));
                mx[r] = rmax16(v);
            }
            int small = (mx[0] - m[rt][0] <= DEFER) & (mx[1] - m[rt][1] <= DEFER) &
                        (mx[2] - m[rt][2] <= DEFER) & (mx[3] - m[rt][3] <= DEFER);
            if (!__all(small)) {
#pragma unroll
                for (int r = 0; r < 4; ++r) {
                    float mn = fmaxf(m[rt][r], mx[r]);
                    float alpha = exp2f(m[rt][r] - mn);
                    m[rt][r] = mn;
                    lacc[rt][r] *= alpha;
#pragma unroll
                    for (int df = 0; df < 4; ++df) O[rt][df][r] *= alpha;
                }
            }
#pragma unroll
            for (int f = 0; f < 4; ++f)
#pragma unroll
                for (int r = 0; r < 4; ++r)
                    sf[rt][f][r] = exp2f(sf[rt][f][r] - m[rt][r]);
        }

        // ---- P -> per-wave LDS (swizzled), read back as A-fragments ----
        char* pw = plds[wave];
#pragma unroll
        for (int rt = 0; rt < 2; ++rt)
#pragma unroll
            for (int f = 0; f < 4; ++f)
#pragma unroll
                for (int r = 0; r < 4; ++r) {
                    int prow = rt * 16 + g4 + r;
                    int off = prow * 128 + (((f * 16 + lrow) * 2) ^ ((prow & 7) << 4));
                    *(__bf16*)(pw + off) = (__bf16)sf[rt][f][r];
                }
        bf16x8 pf[2][2];
#pragma unroll
        for (int rt = 0; rt < 2; ++rt)
#pragma unroll
            for (int ks = 0; ks < 2; ++ks) {
                int prow = rt * 16 + lrow;
                int off = prow * 128 + (((ks * 32 + lk8) * 2) ^ ((prow & 7) << 4));
                pf[rt][ks] = *(const bf16x8*)(pw + off);
            }

        // ---- l += rowsum(P) via MFMA-ones; O += P V ----
#pragma unroll
        for (int rt = 0; rt < 2; ++rt) {
            lacc[rt] = MFMA16(pf[rt][0], ones, lacc[rt]);
            lacc[rt] = MFMA16(pf[rt][1], ones, lacc[rt]);
        }
#pragma unroll
        for (int df = 0; df < 4; ++df) {
#pragma unroll
            for (int ks = 0; ks < 2; ++ks) {
                int d = df * 16 + lrow;
                int off = d * 128 + (((ks * 32 + lk8) * 2) ^ ((d & 7) << 4));
                bf16x8 vf = *(const bf16x8*)(Vtl + off);
                O[0][df] = MFMA16(pf[0][ks], vf, O[0][df]);
                O[1][df] = MFMA16(pf[1][ks], vf, O[1][df]);
            }
        }

        block_sync();  // barrier B: all waves done reading kvlds[buf]
        buf ^= 1;
    }

    // ---- epilogue ----
#pragma unroll
    for (int rt = 0; rt < 2; ++rt)
#pragma unroll
        for (int df = 0; df < 4; ++df)
#pragma unroll
            for (int r = 0; r < 4; ++r) {
                int row = rowbase + rt * 16 + g4 + r;
                out[hoff + (size_t)row * DK + df * 16 + lrow] = O[rt][df][r] / lacc[rt][r];
            }
}

// ---------------------------------------------------------------------------
extern "C" void kernel_launch(void* const* d_in, const int* in_sizes, int n_in,
                              void* d_out, int out_size, void* d_ws, size_t ws_size,
                              hipStream_t stream) {
    const float* x = (const float*)d_in[0];
    const float* qp = (const float*)d_in[1];
    const float* kp = (const float*)d_in[2];
    const float* vp = (const float*)d_in[3];
    float* out = (float*)d_out;

    const size_t WT_SZ = (size_t)NH * DK * E * 2;     // 1,179,648 B
    const size_t QKV_SZ = (size_t)NH * SEQ * DK * 2;  // 6,291,456 B
    const size_t X_SZ = (size_t)SEQ * E * 2;          // 6,291,456 B
    char* ws = (char*)d_ws;
    __bf16* wtq_h = (__bf16*)(ws + 0 * WT_SZ);
    __bf16* wtq_l = (__bf16*)(ws + 1 * WT_SZ);
    __bf16* wtk_h = (__bf16*)(ws + 2 * WT_SZ);
    __bf16* wtk_l = (__bf16*)(ws + 3 * WT_SZ);
    __bf16* wtv_h = (__bf16*)(ws + 4 * WT_SZ);
    char* p2 = ws + 5 * WT_SZ;
    __bf16* qh = (__bf16*)(p2 + 0 * QKV_SZ);
    __bf16* ql = (__bf16*)(p2 + 1 * QKV_SZ);
    __bf16* kh = (__bf16*)(p2 + 2 * QKV_SZ);
    __bf16* kl = (__bf16*)(p2 + 3 * QKV_SZ);
    __bf16* vt = (__bf16*)(p2 + 4 * QKV_SZ);
    char* p3 = p2 + 5 * QKV_SZ;
    __bf16* xh = (__bf16*)(p3 + 0 * X_SZ);
    __bf16* xl = (__bf16*)(p3 + 1 * X_SZ);

    hipLaunchKernelGGL(xsplit_kernel, dim3(SEQ * E / 4 / 256), dim3(256), 0, stream,
                       x, xh, xl);
    hipLaunchKernelGGL(wsplit_kernel, dim3((NH * E * DK + 255) / 256), dim3(256), 0, stream,
                       qp, kp, vp, wtq_h, wtq_l, wtk_h, wtk_l, wtv_h);
    hipLaunchKernelGGL(proj_qk_kernel, dim3(192), dim3(256), 0, stream,
                       xh, xl, wtq_h, wtq_l, qh, ql);
    hipLaunchKernelGGL(proj_qk_kernel, dim3(192), dim3(256), 0, stream,
                       xh, xl, wtk_h, wtk_l, kh, kl);
    hipLaunchKernelGGL(proj_v_kernel, dim3(192), dim3(256), 0, stream,
                       xh, wtv_h, vt);
    hipLaunchKernelGGL(attn_kernel, dim3(384), dim3(256), 0, stream,
                       qh, ql, kh, kl, vt, out);
}

// Round 5
// 262.946 us; speedup vs baseline: 2.6924x; 1.1949x over previous
//
#include <hip/hip_runtime.h>
#include <hip/hip_bf16.h>

#define NH 12
#define SEQ 4096
#define E 768
#define DK 64

typedef float f32x4 __attribute__((ext_vector_type(4)));
typedef float f32x16 __attribute__((ext_vector_type(16)));
typedef __bf16 bf16x8 __attribute__((ext_vector_type(8)));
typedef __bf16 bf16x4 __attribute__((ext_vector_type(4)));
typedef unsigned u32x2 __attribute__((ext_vector_type(2)));
typedef unsigned u32x4 __attribute__((ext_vector_type(4)));

#define MFMA16(a, b, c) __builtin_amdgcn_mfma_f32_16x16x32_bf16((a), (b), (c), 0, 0, 0)
#define MFMA32(a, b, c) __builtin_amdgcn_mfma_f32_32x32x16_bf16((a), (b), (c), 0, 0, 0)

// log2(e) / sqrt(dk); folded into K weights at wsplit time.
#define SCL 0.18033688011112042f
// defer-max threshold in log2 units: P bounded by 2^10.8
#define DEFER 10.8f

__device__ __forceinline__ void gload16(const void* g, void* l) {
    __builtin_amdgcn_global_load_lds(
        (const __attribute__((address_space(1))) void*)g,
        (__attribute__((address_space(3))) void*)l, 16, 0, 0);
}

__device__ __forceinline__ void block_sync() {
    __builtin_amdgcn_sched_barrier(0);
    __builtin_amdgcn_s_barrier();
    __builtin_amdgcn_sched_barrier(0);
}

__device__ __forceinline__ unsigned cvtpk(float lo, float hi) {
    unsigned r;
    asm("v_cvt_pk_bf16_f32 %0, %1, %2" : "=v"(r) : "v"(lo), "v"(hi));
    return r;
}
__device__ __forceinline__ u32x2 plswap(unsigned a, unsigned b) {
    return __builtin_amdgcn_permlane32_swap(a, b, false, false);
}
// combine a per-lane value with its cross-half partner (lane ^ 32)
__device__ __forceinline__ float xhalf_max(float v) {
    u32x2 r = plswap(__float_as_uint(v), __float_as_uint(v));
    return fmaxf(__uint_as_float(r.x), __uint_as_float(r.y));
}
__device__ __forceinline__ float xhalf_add(float v) {
    u32x2 r = plswap(__float_as_uint(v), __float_as_uint(v));
    return __uint_as_float(r.x) + __uint_as_float(r.y);
}

// ---------------------------------------------------------------------------
// Kernel 0: split x into bf16 hi/lo
// ---------------------------------------------------------------------------
__global__ __launch_bounds__(256) void xsplit_kernel(const float* __restrict__ x,
                                                     __bf16* __restrict__ xh,
                                                     __bf16* __restrict__ xl) {
    int i = blockIdx.x * blockDim.x + threadIdx.x;
    float4 v = ((const float4*)x)[i];
    bf16x4 h, l;
    float vv[4] = {v.x, v.y, v.z, v.w};
#pragma unroll
    for (int j = 0; j < 4; ++j) {
        __bf16 hh = (__bf16)vv[j];
        h[j] = hh;
        l[j] = (__bf16)(vv[j] - (float)hh);
    }
    ((bf16x4*)xh)[i] = h;
    ((bf16x4*)xl)[i] = l;
}

// ---------------------------------------------------------------------------
// Kernel 1: split projection weights (hi/lo), transpose to [h][n][k].
// K weights pre-scaled by SCL so attention scores come out in log2 units.
// ---------------------------------------------------------------------------
__global__ void wsplit_kernel(const float* __restrict__ qp,
                              const float* __restrict__ kp,
                              const float* __restrict__ vp,
                              __bf16* __restrict__ wtq_h, __bf16* __restrict__ wtq_l,
                              __bf16* __restrict__ wtk_h, __bf16* __restrict__ wtk_l,
                              __bf16* __restrict__ wtv_h) {
    int idx = blockIdx.x * blockDim.x + threadIdx.x;
    if (idx >= NH * E * DK) return;
    int h = idx / (E * DK);
    int rem = idx - h * E * DK;
    int k = rem / DK;
    int n = rem - k * DK;
    int o = h * DK * E + n * E + k;  // [h][n][k]
    float q = qp[idx];
    __bf16 qh = (__bf16)q;
    wtq_h[o] = qh;
    wtq_l[o] = (__bf16)(q - (float)qh);
    float kk = kp[idx] * SCL;
    __bf16 kh = (__bf16)kk;
    wtk_h[o] = kh;
    wtk_l[o] = (__bf16)(kk - (float)kh);
    wtv_h[o] = (__bf16)vp[idx];
}

// ---------------------------------------------------------------------------
// Kernel 2a: fused Q+K projection. Block = 256 rows x 1 head, 4 waves x 64
// rows (rt=4). Wq/Wk hi+lo staged in LDS (dbuf, counted vmcnt); x read once.
// ---------------------------------------------------------------------------
__global__ __launch_bounds__(256, 2) void proj_qk_kernel(
    const __bf16* __restrict__ xh, const __bf16* __restrict__ xl,
    const __bf16* __restrict__ wq_h_g, const __bf16* __restrict__ wq_l_g,
    const __bf16* __restrict__ wk_h_g, const __bf16* __restrict__ wk_l_g,
    __bf16* __restrict__ qh_o, __bf16* __restrict__ ql_o,
    __bf16* __restrict__ kh_o, __bf16* __restrict__ kl_o) {
    __shared__ char wlds[2][16384];  // [buf][ Wqh 4K | Wql 4K | Wkh 4K | Wkl 4K ]

    const int wg = (blockIdx.x & 7) * 24 + (blockIdx.x >> 3);  // 192 = 8 x 24
    const int head = wg % NH;
    const int rb = wg / NH;  // 0..15
    const int wave = threadIdx.x >> 6;
    const int lane = threadIdx.x & 63;
    const int lrow = lane & 15;
    const int lk8 = (lane >> 4) * 8;
    const int g4 = (lane >> 4) * 4;
    const int rowbase = rb * 256 + wave * 64;

    const char* wq_h_b = (const char*)(wq_h_g + head * DK * E);
    const char* wq_l_b = (const char*)(wq_l_g + head * DK * E);
    const char* wk_h_b = (const char*)(wk_h_g + head * DK * E);
    const char* wk_l_b = (const char*)(wk_l_g + head * DK * E);
    // each wave stages one matrix (wave 0..3 -> Wqh, Wql, Wkh, Wkl)
    const char* base = (wave == 0) ? wq_h_b : (wave == 1) ? wq_l_b
                      : (wave == 2) ? wk_h_b : wk_l_b;
    const int srow = lane >> 2;        // 0..15
    const int scol = (lane & 3) * 16;  // byte in 64B row-slice

    auto STAGE = [&](int buf, int ks) {
#pragma unroll
        for (int r = 0; r < 4; ++r) {
            const char* src = base + (size_t)(r * 16 + srow) * (E * 2) + ks * 64 + scol;
            gload16(src, wlds[buf] + (wave * 4 + r) * 1024 + lane * 16);
        }
    };

    f32x4 accq[4][4], acck[4][4];
#pragma unroll
    for (int rt = 0; rt < 4; ++rt)
#pragma unroll
        for (int f = 0; f < 4; ++f) {
            accq[rt][f] = (f32x4){0.f, 0.f, 0.f, 0.f};
            acck[rt][f] = (f32x4){0.f, 0.f, 0.f, 0.f};
        }

    bf16x8 ah[4], al[4], ahn[4], aln[4];
    auto LOADA = [&](int ks, bf16x8* h, bf16x8* l) {
#pragma unroll
        for (int rt = 0; rt < 4; ++rt) {
            size_t xo = (size_t)(rowbase + rt * 16 + lrow) * E + ks * 32 + lk8;
            h[rt] = *(const bf16x8*)(xh + xo);
            l[rt] = *(const bf16x8*)(xl + xo);
        }
    };

    LOADA(0, ah, al);
    STAGE(0, 0);
    int buf = 0;
    for (int ks = 0; ks < 24; ++ks) {
        if (ks < 23) {
            LOADA(ks + 1, ahn, aln);
            STAGE(buf ^ 1, ks + 1);
            asm volatile("s_waitcnt vmcnt(12)" ::: "memory");
        } else {
            asm volatile("s_waitcnt vmcnt(0)" ::: "memory");
        }
        block_sync();
#pragma unroll
        for (int f = 0; f < 4; ++f) {
            int bo = (f * 16 + lrow) * 64 + lk8 * 2;
            bf16x8 bqh = *(const bf16x8*)(wlds[buf] + bo);
            bf16x8 bql = *(const bf16x8*)(wlds[buf] + 4096 + bo);
            bf16x8 bkh = *(const bf16x8*)(wlds[buf] + 8192 + bo);
            bf16x8 bkl = *(const bf16x8*)(wlds[buf] + 12288 + bo);
#pragma unroll
            for (int rt = 0; rt < 4; ++rt) {
                accq[rt][f] = MFMA16(ah[rt], bqh, accq[rt][f]);
                accq[rt][f] = MFMA16(ah[rt], bql, accq[rt][f]);
                accq[rt][f] = MFMA16(al[rt], bqh, accq[rt][f]);
                acck[rt][f] = MFMA16(ah[rt], bkh, acck[rt][f]);
                acck[rt][f] = MFMA16(ah[rt], bkl, acck[rt][f]);
                acck[rt][f] = MFMA16(al[rt], bkh, acck[rt][f]);
            }
        }
        block_sync();
        if (ks < 23) {
#pragma unroll
            for (int rt = 0; rt < 4; ++rt) {
                ah[rt] = ahn[rt];
                al[rt] = aln[rt];
            }
        }
        buf ^= 1;
    }

#pragma unroll
    for (int rt = 0; rt < 4; ++rt)
#pragma unroll
        for (int f = 0; f < 4; ++f)
#pragma unroll
            for (int r = 0; r < 4; ++r) {
                int srow_o = rowbase + rt * 16 + g4 + r;
                int d = f * 16 + lrow;
                size_t o = (size_t)head * SEQ * DK + (size_t)srow_o * DK + d;
                float qv = accq[rt][f][r];
                __bf16 qhh = (__bf16)qv;
                qh_o[o] = qhh;
                ql_o[o] = (__bf16)(qv - (float)qhh);
                float kv = acck[rt][f][r];
                __bf16 khh = (__bf16)kv;
                kh_o[o] = khh;
                kl_o[o] = (__bf16)(kv - (float)khh);
            }
}

// ---------------------------------------------------------------------------
// Kernel 2b: V projection (1-term, operand-swapped -> coalesced V^T stores).
// ---------------------------------------------------------------------------
__global__ __launch_bounds__(256) void proj_v_kernel(
    const __bf16* __restrict__ xh, const __bf16* __restrict__ w_v,
    __bf16* __restrict__ vt_o) {
    __shared__ char wlds[2][4096];

    const int wg = (blockIdx.x & 7) * 24 + (blockIdx.x >> 3);
    const int head = wg % NH;
    const int rb = wg / NH;
    const int wave = threadIdx.x >> 6;
    const int lane = threadIdx.x & 63;
    const int lrow = lane & 15;
    const int lk8 = (lane >> 4) * 8;
    const int g4 = (lane >> 4) * 4;
    const int rowbase = rb * 256 + wave * 64;

    const char* wv_b = (const char*)(w_v + head * DK * E);
    const int srow = lane >> 2;
    const int scol = (lane & 3) * 16;

    auto STAGE = [&](int buf, int ks) {
        const char* src = wv_b + (size_t)(wave * 16 + srow) * (E * 2) + ks * 64 + scol;
        gload16(src, wlds[buf] + wave * 1024 + lane * 16);
    };

    f32x4 acc[4][4];
#pragma unroll
    for (int rt = 0; rt < 4; ++rt)
#pragma unroll
        for (int f = 0; f < 4; ++f) acc[rt][f] = (f32x4){0.f, 0.f, 0.f, 0.f};

    bf16x8 ah[4], ahn[4];
    auto LOADA = [&](int ks, bf16x8* h) {
#pragma unroll
        for (int rt = 0; rt < 4; ++rt) {
            size_t xo = (size_t)(rowbase + rt * 16 + lrow) * E + ks * 32 + lk8;
            h[rt] = *(const bf16x8*)(xh + xo);
        }
    };

    LOADA(0, ah);
    STAGE(0, 0);
    int buf = 0;
    for (int ks = 0; ks < 24; ++ks) {
        if (ks < 23) {
            LOADA(ks + 1, ahn);
            STAGE(buf ^ 1, ks + 1);
            asm volatile("s_waitcnt vmcnt(5)" ::: "memory");
        } else {
            asm volatile("s_waitcnt vmcnt(0)" ::: "memory");
        }
        block_sync();
#pragma unroll
        for (int f = 0; f < 4; ++f) {
            int bo = (f * 16 + lrow) * 64 + lk8 * 2;
            bf16x8 bv = *(const bf16x8*)(wlds[buf] + bo);
#pragma unroll
            for (int rt = 0; rt < 4; ++rt)
                acc[rt][f] = MFMA16(bv, ah[rt], acc[rt][f]);  // D[d][s]
        }
        block_sync();
        if (ks < 23) {
#pragma unroll
            for (int rt = 0; rt < 4; ++rt) ah[rt] = ahn[rt];
        }
        buf ^= 1;
    }

#pragma unroll
    for (int rt = 0; rt < 4; ++rt)
#pragma unroll
        for (int f = 0; f < 4; ++f)
#pragma unroll
            for (int r = 0; r < 4; ++r) {
                int vd = f * 16 + g4 + r;
                int vs = rowbase + rt * 16 + lrow;
                vt_o[(size_t)head * DK * SEQ + (size_t)vd * SEQ + vs] = (__bf16)acc[rt][f][r];
            }
}

// ---------------------------------------------------------------------------
// Kernel 3: causal flash attention, swapped 32x32x16 MFMA, in-register P.
// Block = 256 thr (4 waves x 32 q-rows, QB=128), KVB=64.
// S = mfma(K, Q): lane owns q-row lane&31 -> softmax is lane-local + one
// permlane32_swap. P -> PV A-frags via cvt_pk + permlane32_swap (no LDS).
// K(hi,lo)/V^T staged via global_load_lds (dbuf, swizzled src, vmcnt(6)).
// ---------------------------------------------------------------------------
__global__ __launch_bounds__(256, 2) void attn_kernel(
    const __bf16* __restrict__ qh, const __bf16* __restrict__ ql,
    const __bf16* __restrict__ kh, const __bf16* __restrict__ kl,
    const __bf16* __restrict__ vt,
    float* __restrict__ out) {
    __shared__ char kvlds[2][24576];  // [buf][ Kh 8K | Kl 8K | Vt 8K ]
    __shared__ float bbuf[4][32];     // per-wave broadcast (alpha / 1/l)

    const int wg = (blockIdx.x & 7) * 48 + (blockIdx.x >> 3);  // 384 = 8 x 48
    const int head = wg >> 5;
    const int qb = 31 - (wg & 31);  // heavy-first
    const int q0 = qb * 128;
    const int wave = threadIdx.x >> 6;
    const int lane = threadIdx.x & 63;
    const int lq = lane & 31;
    const int lh = lane >> 5;
    const int swz = (lq & 7) << 4;

    const size_t hoff = (size_t)head * SEQ * DK;
    const int rowbase = q0 + wave * 32;

    // Q B-frags (hoisted): lane holds Q[rowbase+lq][ds*16 + lh*8 + 0..7]
    bf16x8 qBh[4], qBl[4];
    {
        const __bf16* qp = qh + hoff + (size_t)(rowbase + lq) * DK + lh * 8;
        const __bf16* lp = ql + hoff + (size_t)(rowbase + lq) * DK + lh * 8;
#pragma unroll
        for (int ds = 0; ds < 4; ++ds) {
            qBh[ds] = *(const bf16x8*)(qp + ds * 16);
            qBl[ds] = *(const bf16x8*)(lp + ds * 16);
        }
    }
    asm volatile("s_waitcnt vmcnt(0)" ::: "memory");  // clean vmcnt baseline

    const char* kh_b = (const char*)(kh + hoff);
    const char* kl_b = (const char*)(kl + hoff);
    const char* vt_b = (const char*)(vt + (size_t)head * DK * SEQ);

    const int slr = lane >> 3;        // staging row-within-chunk
    const int scb = (lane & 7) * 16;  // staging col byte

    f32x16 O0 = (f32x16)0.0f, O1 = (f32x16)0.0f;
    float m = -3.0e38f, lsum = 0.f;

    const int nt = 2 * qb + 2;

    auto STAGE = [&](int buf, int kb) {
        char* dst = kvlds[buf];
        const char* khs = kh_b + (size_t)kb * (DK * 2);
        const char* kls = kl_b + (size_t)kb * (DK * 2);
        const char* vts = vt_b + (size_t)kb * 2;
#pragma unroll
        for (int r = 0; r < 6; ++r) {
            int q = r * 4 + wave;
            int c = q & 7;
            int row = c * 8 + slr;
            int scol = scb ^ ((row & 7) << 4);
            const char* src;
            if (q < 8)       src = khs + row * 128 + scol;
            else if (q < 16) src = kls + row * 128 + scol;
            else             src = vts + (size_t)row * (SEQ * 2) + scol;
            gload16(src, dst + q * 1024);
        }
    };

    STAGE(0, 0);
    int buf = 0;

    for (int t = 0; t < nt; ++t) {
        const int kb = t * 64;
        if (t + 1 < nt) {
            STAGE(buf ^ 1, (t + 1) * 64);
            asm volatile("s_waitcnt vmcnt(6)" ::: "memory");
        } else {
            asm volatile("s_waitcnt vmcnt(0)" ::: "memory");
        }
        block_sync();  // tile-t data in LDS

        if (kb <= rowbase + 31) {  // wave has unmasked work in this tile
            const char* Khl = kvlds[buf];
            const char* Kll = kvlds[buf] + 8192;
            const char* Vtl = kvlds[buf] + 16384;

            // ---- S = K'^T Q (swapped; log2 units). s0: kpos 0..31, s1: 32..63
            f32x16 s0 = (f32x16)0.0f, s1 = (f32x16)0.0f;
#pragma unroll
            for (int ds = 0; ds < 4; ++ds) {
                int co = (ds * 32 + lh * 16) ^ swz;
                int o0 = lq * 128 + co;
                bf16x8 ah0 = *(const bf16x8*)(Khl + o0);
                bf16x8 al0 = *(const bf16x8*)(Kll + o0);
                bf16x8 ah1 = *(const bf16x8*)(Khl + o0 + 4096);
                bf16x8 al1 = *(const bf16x8*)(Kll + o0 + 4096);
                s0 = MFMA32(ah0, qBh[ds], s0);
                s1 = MFMA32(ah1, qBh[ds], s1);
                s0 = MFMA32(al0, qBh[ds], s0);
                s1 = MFMA32(al1, qBh[ds], s1);
                s0 = MFMA32(ah0, qBl[ds], s0);
                s1 = MFMA32(ah1, qBl[ds], s1);
            }

            // ---- causal mask (S layout: row kpos=(r&3)+8*(r>>2)+4lh, col q=lq)
            if (kb + 63 > rowbase) {
                int qa = rowbase + lq;
#pragma unroll
                for (int r = 0; r < 16; ++r) {
                    int kp = kb + ((r & 3) + 8 * (r >> 2) + 4 * lh);
                    if (kp > qa) s0[r] = -1.0e30f;
                    if (kp + 32 > qa) s1[r] = -1.0e30f;
                }
            }

            // ---- row max: 4-chain tree + one cross-half swap ----
            float x0 = fmaxf(s0[0], s0[1]), x1 = fmaxf(s0[2], s0[3]);
            float x2 = fmaxf(s0[4], s0[5]), x3 = fmaxf(s0[6], s0[7]);
#pragma unroll
            for (int r = 8; r < 16; r += 4) {
                x0 = fmaxf(x0, fmaxf(s0[r], s0[r + 1]));
                x1 = fmaxf(x1, fmaxf(s0[r + 2], s0[r + 3]));
            }
#pragma unroll
            for (int r = 0; r < 16; r += 4) {
                x2 = fmaxf(x2, fmaxf(s1[r], s1[r + 1]));
                x3 = fmaxf(x3, fmaxf(s1[r + 2], s1[r + 3]));
            }
            float mx = xhalf_max(fmaxf(fmaxf(x0, x1), fmaxf(x2, x3)));

            // ---- defer-max rescale (rare-ish) ----
            if (!__all(mx - m <= DEFER)) {
                float mn = fmaxf(m, mx);
                float al = exp2f(m - mn);
                m = mn;
                lsum *= al;
                if (lane < 32) bbuf[wave][lq] = al;
                asm volatile("s_waitcnt lgkmcnt(0)" ::: "memory");
                __builtin_amdgcn_sched_barrier(0);
#pragma unroll
                for (int r = 0; r < 16; ++r) {
                    float a = bbuf[wave][(r & 3) + 8 * (r >> 2) + 4 * lh];
                    O0[r] *= a;
                    O1[r] *= a;
                }
            }

            // ---- P = exp2(S - m); l accumulation (4-chain) ----
#pragma unroll
            for (int r = 0; r < 16; ++r) {
                s0[r] = exp2f(s0[r] - m);
                s1[r] = exp2f(s1[r] - m);
            }
            {
                float p0 = 0.f, p1 = 0.f, p2 = 0.f, p3 = 0.f;
#pragma unroll
                for (int r = 0; r < 16; r += 4) {
                    p0 += s0[r] + s0[r + 1];
                    p1 += s0[r + 2] + s0[r + 3];
                    p2 += s1[r] + s1[r + 1];
                    p3 += s1[r + 2] + s1[r + 3];
                }
                lsum += (p0 + p1) + (p2 + p3);
            }

            // ---- P -> PV A-frags: cvt_pk + permlane32_swap (in-register) ----
            unsigned W0 = cvtpk(s0[0], s0[1]), W1 = cvtpk(s0[2], s0[3]);
            unsigned W2 = cvtpk(s0[4], s0[5]), W3 = cvtpk(s0[6], s0[7]);
            unsigned W4 = cvtpk(s0[8], s0[9]), W5 = cvtpk(s0[10], s0[11]);
            unsigned W6 = cvtpk(s0[12], s0[13]), W7 = cvtpk(s0[14], s0[15]);
            u32x2 rA = plswap(W0, W2), rB = plswap(W1, W3);
            u32x2 rC = plswap(W4, W6), rD = plswap(W5, W7);
            bf16x8 p00 = __builtin_bit_cast(bf16x8, (u32x4){rA.x, rB.x, rA.y, rB.y});
            bf16x8 p01 = __builtin_bit_cast(bf16x8, (u32x4){rC.x, rD.x, rC.y, rD.y});
            W0 = cvtpk(s1[0], s1[1]); W1 = cvtpk(s1[2], s1[3]);
            W2 = cvtpk(s1[4], s1[5]); W3 = cvtpk(s1[6], s1[7]);
            W4 = cvtpk(s1[8], s1[9]); W5 = cvtpk(s1[10], s1[11]);
            W6 = cvtpk(s1[12], s1[13]); W7 = cvtpk(s1[14], s1[15]);
            rA = plswap(W0, W2); rB = plswap(W1, W3);
            rC = plswap(W4, W6); rD = plswap(W5, W7);
            bf16x8 p10 = __builtin_bit_cast(bf16x8, (u32x4){rA.x, rB.x, rA.y, rB.y});
            bf16x8 p11 = __builtin_bit_cast(bf16x8, (u32x4){rC.x, rD.x, rC.y, rD.y});

            // ---- O += P V (V B-frags direct from swizzled LDS) ----
#pragma unroll
            for (int dt = 0; dt < 2; ++dt) {
                int rb_ = (dt * 32 + lq) * 128;
                bf16x8 v00 = *(const bf16x8*)(Vtl + rb_ + ((0 + lh * 16) ^ swz));
                bf16x8 v01 = *(const bf16x8*)(Vtl + rb_ + ((32 + lh * 16) ^ swz));
                bf16x8 v10 = *(const bf16x8*)(Vtl + rb_ + ((64 + lh * 16) ^ swz));
                bf16x8 v11 = *(const bf16x8*)(Vtl + rb_ + ((96 + lh * 16) ^ swz));
                if (dt == 0) {
                    O0 = MFMA32(p00, v00, O0);
                    O0 = MFMA32(p01, v01, O0);
                    O0 = MFMA32(p10, v10, O0);
                    O0 = MFMA32(p11, v11, O0);
                } else {
                    O1 = MFMA32(p00, v00, O1);
                    O1 = MFMA32(p01, v01, O1);
                    O1 = MFMA32(p10, v10, O1);
                    O1 = MFMA32(p11, v11, O1);
                }
            }
        }

        block_sync();  // all waves done reading kvlds[buf]
        buf ^= 1;
    }

    // ---- epilogue: combine l halves, broadcast 1/l, store ----
    float lf = xhalf_add(lsum);
    if (lane < 32) bbuf[wave][lq] = 1.0f / lf;
    asm volatile("s_waitcnt lgkmcnt(0)" ::: "memory");
    __builtin_amdgcn_sched_barrier(0);
#pragma unroll
    for (int r = 0; r < 16; ++r) {
        int rr = (r & 3) + 8 * (r >> 2) + 4 * lh;
        float li = bbuf[wave][rr];
        size_t o = hoff + (size_t)(rowbase + rr) * DK + lq;
        out[o] = O0[r] * li;
        out[o + 32] = O1[r] * li;
    }
}

// ---------------------------------------------------------------------------
extern "C" void kernel_launch(void* const* d_in, const int* in_sizes, int n_in,
                              void* d_out, int out_size, void* d_ws, size_t ws_size,
                              hipStream_t stream) {
    const float* x = (const float*)d_in[0];
    const float* qp = (const float*)d_in[1];
    const float* kp = (const float*)d_in[2];
    const float* vp = (const float*)d_in[3];
    float* out = (float*)d_out;

    const size_t WT_SZ = (size_t)NH * DK * E * 2;     // 1,179,648 B
    const size_t QKV_SZ = (size_t)NH * SEQ * DK * 2;  // 6,291,456 B
    const size_t X_SZ = (size_t)SEQ * E * 2;          // 6,291,456 B
    char* ws = (char*)d_ws;
    __bf16* wtq_h = (__bf16*)(ws + 0 * WT_SZ);
    __bf16* wtq_l = (__bf16*)(ws + 1 * WT_SZ);
    __bf16* wtk_h = (__bf16*)(ws + 2 * WT_SZ);
    __bf16* wtk_l = (__bf16*)(ws + 3 * WT_SZ);
    __bf16* wtv_h = (__bf16*)(ws + 4 * WT_SZ);
    char* p2 = ws + 5 * WT_SZ;
    __bf16* qh = (__bf16*)(p2 + 0 * QKV_SZ);
    __bf16* ql = (__bf16*)(p2 + 1 * QKV_SZ);
    __bf16* kh = (__bf16*)(p2 + 2 * QKV_SZ);
    __bf16* kl = (__bf16*)(p2 + 3 * QKV_SZ);
    __bf16* vt = (__bf16*)(p2 + 4 * QKV_SZ);
    char* p3 = p2 + 5 * QKV_SZ;
    __bf16* xh = (__bf16*)(p3 + 0 * X_SZ);
    __bf16* xl = (__bf16*)(p3 + 1 * X_SZ);

    hipLaunchKernelGGL(xsplit_kernel, dim3(SEQ * E / 4 / 256), dim3(256), 0, stream,
                       x, xh, xl);
    hipLaunchKernelGGL(wsplit_kernel, dim3((NH * E * DK + 255) / 256), dim3(256), 0, stream,
                       qp, kp, vp, wtq_h, wtq_l, wtk_h, wtk_l, wtv_h);
    hipLaunchKernelGGL(proj_qk_kernel, dim3(192), dim3(256), 0, stream,
                       xh, xl, wtq_h, wtq_l, wtk_h, wtk_l, qh, ql, kh, kl);
    hipLaunchKernelGGL(proj_v_kernel, dim3(192), dim3(256), 0, stream,
                       xh, wtv_h, vt);
    hipLaunchKernelGGL(attn_kernel, dim3(384), dim3(256), 0, stream,
                       qh, ql, kh, kl, vt, out);
}